// Round 4
// baseline (574.425 us; speedup 1.0000x reference)
//
#include <hip/hip_runtime.h>
#include <math.h>

namespace {

constexpr int Bn = 8;
constexpr int Sn = 1024;
constexpr int Dn = 256;
constexpr int Mn = Bn * Sn;   // 8192 rows
constexpr int CT = 8;         // scan chunk length (steps)
constexpr int NC = Sn / CT;   // 128 chunks

__device__ float g_den[Bn * Sn];   // raw n·q per (b,t); clamp applied in out_gemm

__device__ __forceinline__ float sigmoidf_(float x) {
    return 1.0f / (1.0f + __expf(-x));
}

// ---- async global->LDS staging (width 16) -------------------------------
__device__ __forceinline__ void cp16(const float* g, float* l) {
    __builtin_amdgcn_global_load_lds(
        (const __attribute__((address_space(1))) void*)g,
        (__attribute__((address_space(3))) void*)l, 16, 0, 0);
}
// s_waitcnt immediates (gfx9 encoding: vm lo[3:0], exp[6:4], lgkm[11:8], vm hi[15:14])
__device__ __forceinline__ void wait_vm0()  { asm volatile("" ::: "memory"); __builtin_amdgcn_s_waitcnt(0x0F70); asm volatile("" ::: "memory"); }
__device__ __forceinline__ void wait_vm8()  { asm volatile("" ::: "memory"); __builtin_amdgcn_s_waitcnt(0x0F78); asm volatile("" ::: "memory"); }
__device__ __forceinline__ void wait_vm16() { asm volatile("" ::: "memory"); __builtin_amdgcn_s_waitcnt(0x4F70); asm volatile("" ::: "memory"); }
__device__ __forceinline__ void wait_lgkm0(){ asm volatile("" ::: "memory"); __builtin_amdgcn_s_waitcnt(0xC07F); asm volatile("" ::: "memory"); }
__device__ __forceinline__ void barrier_raw(){ asm volatile("" ::: "memory"); __builtin_amdgcn_s_barrier(); asm volatile("" ::: "memory"); }

// ---------------------------------------------------------------------------
// Fused projection GEMM: Y_m = act_m(X @ W_m^T + b_m) for m in {q,k,f,i}
// ---------------------------------------------------------------------------
__global__ __launch_bounds__(256) void proj_gemm(
    const float* __restrict__ X,
    const float* __restrict__ W0, const float* __restrict__ b0,
    const float* __restrict__ W1, const float* __restrict__ b1,
    const float* __restrict__ W2, const float* __restrict__ b2,
    const float* __restrict__ W3, const float* __restrict__ b3,
    float* __restrict__ Y0, float* __restrict__ Y1,
    float* __restrict__ Y2, float* __restrict__ Y3)
{
    __shared__ float As[16][68];
    __shared__ float Bs[4][16][68];

    const int tid = threadIdx.x;
    const int tx = tid & 15;
    const int ty = tid >> 4;
    const int mb = blockIdx.x * 64;
    const int nb = blockIdx.y * 64;
    const int lr = tid >> 2;
    const int lk = (tid & 3) * 4;

    float acc[4][4][4];
    #pragma unroll
    for (int m = 0; m < 4; ++m)
        #pragma unroll
        for (int i = 0; i < 4; ++i)
            #pragma unroll
            for (int j = 0; j < 4; ++j) acc[m][i][j] = 0.0f;

    for (int k0 = 0; k0 < Dn; k0 += 16) {
        const float4 a  = *(const float4*)(X  + (size_t)(mb + lr) * Dn + k0 + lk);
        const float4 w0 = *(const float4*)(W0 + (size_t)(nb + lr) * Dn + k0 + lk);
        const float4 w1 = *(const float4*)(W1 + (size_t)(nb + lr) * Dn + k0 + lk);
        const float4 w2 = *(const float4*)(W2 + (size_t)(nb + lr) * Dn + k0 + lk);
        const float4 w3 = *(const float4*)(W3 + (size_t)(nb + lr) * Dn + k0 + lk);
        __syncthreads();
        As[lk+0][lr] = a.x;  As[lk+1][lr] = a.y;  As[lk+2][lr] = a.z;  As[lk+3][lr] = a.w;
        Bs[0][lk+0][lr] = w0.x; Bs[0][lk+1][lr] = w0.y; Bs[0][lk+2][lr] = w0.z; Bs[0][lk+3][lr] = w0.w;
        Bs[1][lk+0][lr] = w1.x; Bs[1][lk+1][lr] = w1.y; Bs[1][lk+2][lr] = w1.z; Bs[1][lk+3][lr] = w1.w;
        Bs[2][lk+0][lr] = w2.x; Bs[2][lk+1][lr] = w2.y; Bs[2][lk+2][lr] = w2.z; Bs[2][lk+3][lr] = w2.w;
        Bs[3][lk+0][lr] = w3.x; Bs[3][lk+1][lr] = w3.y; Bs[3][lk+2][lr] = w3.z; Bs[3][lk+3][lr] = w3.w;
        __syncthreads();

        #pragma unroll
        for (int kk = 0; kk < 16; ++kk) {
            const float4 av = *(const float4*)&As[kk][ty * 4];
            const float aa[4] = {av.x, av.y, av.z, av.w};
            #pragma unroll
            for (int m = 0; m < 4; ++m) {
                const float4 bv = *(const float4*)&Bs[m][kk][tx * 4];
                const float bb[4] = {bv.x, bv.y, bv.z, bv.w};
                #pragma unroll
                for (int i = 0; i < 4; ++i)
                    #pragma unroll
                    for (int j = 0; j < 4; ++j)
                        acc[m][i][j] = fmaf(aa[i], bb[j], acc[m][i][j]);
            }
        }
    }

    const float4 bb0 = *(const float4*)(b0 + nb + tx * 4);
    const float4 bb1 = *(const float4*)(b1 + nb + tx * 4);
    const float4 bb2 = *(const float4*)(b2 + nb + tx * 4);
    const float4 bb3 = *(const float4*)(b3 + nb + tx * 4);

    #pragma unroll
    for (int i = 0; i < 4; ++i) {
        const size_t rowoff = (size_t)(mb + ty * 4 + i) * Dn + nb + tx * 4;
        float4 o;
        o.x = acc[0][i][0] + bb0.x; o.y = acc[0][i][1] + bb0.y;
        o.z = acc[0][i][2] + bb0.z; o.w = acc[0][i][3] + bb0.w;
        *(float4*)(Y0 + rowoff) = o;
        o.x = acc[1][i][0] + bb1.x; o.y = acc[1][i][1] + bb1.y;
        o.z = acc[1][i][2] + bb1.z; o.w = acc[1][i][3] + bb1.w;
        *(float4*)(Y1 + rowoff) = o;
        o.x = sigmoidf_(acc[2][i][0] + bb2.x); o.y = sigmoidf_(acc[2][i][1] + bb2.y);
        o.z = sigmoidf_(acc[2][i][2] + bb2.z); o.w = sigmoidf_(acc[2][i][3] + bb2.w);
        *(float4*)(Y2 + rowoff) = o;
        o.x = __expf(acc[3][i][0] + bb3.x); o.y = __expf(acc[3][i][1] + bb3.y);
        o.z = __expf(acc[3][i][2] + bb3.z); o.w = __expf(acc[3][i][3] + bb3.w);
        *(float4*)(Y3 + rowoff) = o;
    }
}

// ---------------------------------------------------------------------------
// Output GEMM: out = (num * invden) @ Wo^T + bo  (invden folded into A-load)
// ---------------------------------------------------------------------------
__global__ __launch_bounds__(256) void out_gemm(
    const float* __restrict__ X, const float* __restrict__ W,
    const float* __restrict__ bias, float* __restrict__ Y)
{
    __shared__ float As[16][68];
    __shared__ float Bs[16][68];

    const int tid = threadIdx.x;
    const int tx = tid & 15;
    const int ty = tid >> 4;
    const int mb = blockIdx.x * 64;
    const int nb = blockIdx.y * 64;
    const int lr = tid >> 2;
    const int lk = (tid & 3) * 4;

    const float dn   = g_den[mb + lr];
    const float invd = 1.0f / fmaxf(fabsf(dn), 1.0f);

    float acc[4][4];
    #pragma unroll
    for (int i = 0; i < 4; ++i)
        #pragma unroll
        for (int j = 0; j < 4; ++j) acc[i][j] = 0.0f;

    for (int k0 = 0; k0 < Dn; k0 += 16) {
        float4 a = *(const float4*)(X + (size_t)(mb + lr) * Dn + k0 + lk);
        const float4 w = *(const float4*)(W + (size_t)(nb + lr) * Dn + k0 + lk);
        a.x *= invd; a.y *= invd; a.z *= invd; a.w *= invd;
        __syncthreads();
        As[lk+0][lr] = a.x; As[lk+1][lr] = a.y; As[lk+2][lr] = a.z; As[lk+3][lr] = a.w;
        Bs[lk+0][lr] = w.x; Bs[lk+1][lr] = w.y; Bs[lk+2][lr] = w.z; Bs[lk+3][lr] = w.w;
        __syncthreads();

        #pragma unroll
        for (int kk = 0; kk < 16; ++kk) {
            const float4 av = *(const float4*)&As[kk][ty * 4];
            const float4 bv = *(const float4*)&Bs[kk][tx * 4];
            const float aa[4] = {av.x, av.y, av.z, av.w};
            const float bb[4] = {bv.x, bv.y, bv.z, bv.w};
            #pragma unroll
            for (int i = 0; i < 4; ++i)
                #pragma unroll
                for (int j = 0; j < 4; ++j)
                    acc[i][j] = fmaf(aa[i], bb[j], acc[i][j]);
        }
    }

    const float4 bbv = *(const float4*)(bias + nb + tx * 4);
    #pragma unroll
    for (int i = 0; i < 4; ++i) {
        const size_t rowoff = (size_t)(mb + ty * 4 + i) * Dn + nb + tx * 4;
        float4 o;
        o.x = acc[i][0] + bbv.x; o.y = acc[i][1] + bbv.y;
        o.z = acc[i][2] + bbv.z; o.w = acc[i][3] + bbv.w;
        *(float4*)(Y + rowoff) = o;
    }
}

// ---------------------------------------------------------------------------
// Scan + den with async LDS double-buffered staging.
// Grid (33, B). sb[buf][arr][step][col]: arr 0=k 1=q 2=f 3=i. Wave w stages
// array w (8 rows per chunk -> 8 global_load_lds per wave per chunk).
// Raw s_barrier + manual vmcnt keeps next chunk's DMA in flight.
// ---------------------------------------------------------------------------
__global__ __launch_bounds__(256) void scan_den(
    const float* __restrict__ Pf, const float* __restrict__ Pi,
    const float* __restrict__ Pk, const float* __restrict__ Pq,
    float* __restrict__ Pnum)
{
    __shared__ float sb[2][4][CT][Dn];   // 64 KB staging
    __shared__ float dpart[4][CT];       // den cross-wave partials
    __shared__ float dacc[Sn];           // den results (den block only)

    const int b   = blockIdx.y;
    const int gx  = blockIdx.x;
    const size_t base = (size_t)b * Sn * Dn;

    const float* pk = Pk + base;
    const float* pq = Pq + base;
    const float* pf = Pf + base;
    const float* pI = Pi + base;

    const int tid  = threadIdx.x;
    const int lane = tid & 63;
    const int w    = tid >> 6;

    // this wave's staging source array (k,q,f,i for waves 0..3)
    const float* sarr = (w == 0) ? pk : (w == 1) ? pq : (w == 2) ? pf : pI;

    // prologue: stage chunk 0
    {
        const float* g = sarr + lane * 4;
        #pragma unroll
        for (int j = 0; j < CT; ++j) cp16(g + j * Dn, &sb[0][w][j][0]);
    }

    if (gx == 32) {
        // ================= denominator duty =================
        float n = 0.0f;
        for (int c = 0; c < NC; ++c) {
            const int cur = c & 1;
            if (c + 1 < NC) {
                const float* g = sarr + (size_t)(c + 1) * CT * Dn + lane * 4;
                float* d = &sb[1 - cur][w][0][0];
                #pragma unroll
                for (int j = 0; j < CT; ++j) cp16(g + j * Dn, d + j * Dn);
            }
            if (c + 1 < NC) wait_vm8(); else wait_vm0();
            barrier_raw();

            float p[CT];
            #pragma unroll
            for (int j = 0; j < CT; ++j) {
                const float fv = sb[cur][2][j][tid];
                const float iv = sb[cur][3][j][tid];
                const float kv = sb[cur][0][j][tid];
                const float qv = sb[cur][1][j][tid];
                n = fmaf(fv, n, iv * kv);
                p[j] = n * qv;
            }
            #pragma unroll
            for (int s = 1; s < 64; s <<= 1)
                #pragma unroll
                for (int j = 0; j < CT; ++j)
                    p[j] += __shfl_xor(p[j], s, 64);
            if (lane == 0) {
                #pragma unroll
                for (int j = 0; j < CT; ++j) dpart[w][j] = p[j];
            }
            wait_lgkm0();
            barrier_raw();
            if (tid < CT) {
                dacc[c * CT + tid] = dpart[0][tid] + dpart[1][tid]
                                   + dpart[2][tid] + dpart[3][tid];
            }
            barrier_raw();
        }
        __syncthreads();
        #pragma unroll
        for (int r = 0; r < 4; ++r)
            g_den[b * Sn + r * 256 + tid] = dacc[r * 256 + tid];
        return;
    }

    // ================= C-matrix scan duty =================
    const int r0 = gx * 8 + w * 2;   // this wave's 2 rows
    const int c0 = lane * 4;         // 4 cols per lane
    float* pnum = Pnum + base;

    float C00 = 0.f, C01 = 0.f, C02 = 0.f, C03 = 0.f;
    float C10 = 0.f, C11 = 0.f, C12 = 0.f, C13 = 0.f;

    for (int c = 0; c < NC; ++c) {
        const int cur = c & 1;
        if (c + 1 < NC) {
            const float* g = sarr + (size_t)(c + 1) * CT * Dn + lane * 4;
            float* d = &sb[1 - cur][w][0][0];
            #pragma unroll
            for (int j = 0; j < CT; ++j) cp16(g + j * Dn, d + j * Dn);
        }
        // vmcnt: steady state has loads(c){8} + stores(c-1){8} + loads(c+1){8}
        if (c >= 1 && c <= NC - 2) wait_vm16(); else wait_vm8();
        barrier_raw();

        float m0[CT], m1[CT];
        #pragma unroll
        for (int j = 0; j < CT; ++j) {
            const float4 k4 = *(const float4*)&sb[cur][0][j][c0];
            const float4 q4 = *(const float4*)&sb[cur][1][j][c0];
            const float2 fr = *(const float2*)&sb[cur][2][j][r0];
            const float2 ir = *(const float2*)&sb[cur][3][j][r0];
            const float2 vr = *(const float2*)&sb[cur][1][j][r0];   // v = q proj

            const float w0 = ir.x * vr.x;
            const float w1 = ir.y * vr.y;
            C00 = fmaf(fr.x, C00, w0 * k4.x);
            C01 = fmaf(fr.x, C01, w0 * k4.y);
            C02 = fmaf(fr.x, C02, w0 * k4.z);
            C03 = fmaf(fr.x, C03, w0 * k4.w);
            C10 = fmaf(fr.y, C10, w1 * k4.x);
            C11 = fmaf(fr.y, C11, w1 * k4.y);
            C12 = fmaf(fr.y, C12, w1 * k4.z);
            C13 = fmaf(fr.y, C13, w1 * k4.w);

            float a0 = C00 * q4.x;
            a0 = fmaf(C01, q4.y, a0);
            a0 = fmaf(C02, q4.z, a0);
            a0 = fmaf(C03, q4.w, a0);
            float a1 = C10 * q4.x;
            a1 = fmaf(C11, q4.y, a1);
            a1 = fmaf(C12, q4.z, a1);
            a1 = fmaf(C13, q4.w, a1);
            m0[j] = a0;
            m1[j] = a1;
        }

        #pragma unroll
        for (int s = 1; s < 64; s <<= 1) {
            #pragma unroll
            for (int j = 0; j < CT; ++j) {
                m0[j] += __shfl_xor(m0[j], s, 64);
                m1[j] += __shfl_xor(m1[j], s, 64);
            }
        }

        if (lane < 2) {
            #pragma unroll
            for (int j = 0; j < CT; ++j)
                pnum[(size_t)(c * CT + j) * Dn + r0 + lane] = (lane == 0 ? m0[j] : m1[j]);
        }

        wait_lgkm0();     // drain ds reads before buffer re-stage next iter
        barrier_raw();
    }
}

} // anonymous namespace

extern "C" void kernel_launch(void* const* d_in, const int* in_sizes, int n_in,
                              void* d_out, int out_size, void* d_ws, size_t ws_size,
                              hipStream_t stream)
{
    const float* x  = (const float*)d_in[0];
    const float* Wq = (const float*)d_in[1];  const float* bq = (const float*)d_in[2];
    const float* Wk = (const float*)d_in[3];  const float* bk = (const float*)d_in[4];
    // d_in[5]=Wv, d_in[6]=bv unused (reference uses W_q for v)
    const float* Wf = (const float*)d_in[7];  const float* bf = (const float*)d_in[8];
    const float* Wi = (const float*)d_in[9];  const float* bi = (const float*)d_in[10];
    const float* Wo = (const float*)d_in[11]; const float* bo = (const float*)d_in[12];
    float* out = (float*)d_out;

    float* ws = (float*)d_ws;
    const size_t sz = (size_t)Mn * Dn;     // 8 MB each
    float* Pq = ws;
    float* Pk = ws + sz;
    float* Pf = ws + 2 * sz;
    float* Pi = ws + 3 * sz;
    float* Pn = ws + 4 * sz;               // raw numerators

    proj_gemm<<<dim3(Mn / 64, Dn / 64), 256, 0, stream>>>(
        x, Wq, bq, Wk, bk, Wf, bf, Wi, bi, Pq, Pk, Pf, Pi);

    scan_den<<<dim3(33, Bn), 256, 0, stream>>>(Pf, Pi, Pk, Pq, Pn);

    out_gemm<<<dim3(Mn / 64, Dn / 64), 256, 0, stream>>>(Pn, Wo, bo, out);
}

// Round 5
// 468.090 us; speedup vs baseline: 1.2272x; 1.2272x over previous
//
#include <hip/hip_runtime.h>
#include <math.h>

namespace {

constexpr int Bn = 8;
constexpr int Sn = 1024;
constexpr int Dn = 256;
constexpr int Mn = Bn * Sn;    // 8192 rows
constexpr int NS = 16;         // time segments
constexpr int LS = Sn / NS;    // 64 steps per segment

__device__ float g_den[Bn * Sn];   // raw n·q per (b,t); clamp applied in out_gemm

__device__ __forceinline__ float sigmoidf_(float x) {
    return 1.0f / (1.0f + __expf(-x));
}

// ---------------------------------------------------------------------------
// Fused projection GEMM: Y_m = act_m(X @ W_m^T + b_m) for m in {q,k,f,i}
// ---------------------------------------------------------------------------
__global__ __launch_bounds__(256) void proj_gemm(
    const float* __restrict__ X,
    const float* __restrict__ W0, const float* __restrict__ b0,
    const float* __restrict__ W1, const float* __restrict__ b1,
    const float* __restrict__ W2, const float* __restrict__ b2,
    const float* __restrict__ W3, const float* __restrict__ b3,
    float* __restrict__ Y0, float* __restrict__ Y1,
    float* __restrict__ Y2, float* __restrict__ Y3)
{
    __shared__ float As[16][68];
    __shared__ float Bs[4][16][68];

    const int tid = threadIdx.x;
    const int tx = tid & 15;
    const int ty = tid >> 4;
    const int mb = blockIdx.x * 64;
    const int nb = blockIdx.y * 64;
    const int lr = tid >> 2;
    const int lk = (tid & 3) * 4;

    float acc[4][4][4];
    #pragma unroll
    for (int m = 0; m < 4; ++m)
        #pragma unroll
        for (int i = 0; i < 4; ++i)
            #pragma unroll
            for (int j = 0; j < 4; ++j) acc[m][i][j] = 0.0f;

    for (int k0 = 0; k0 < Dn; k0 += 16) {
        const float4 a  = *(const float4*)(X  + (size_t)(mb + lr) * Dn + k0 + lk);
        const float4 w0 = *(const float4*)(W0 + (size_t)(nb + lr) * Dn + k0 + lk);
        const float4 w1 = *(const float4*)(W1 + (size_t)(nb + lr) * Dn + k0 + lk);
        const float4 w2 = *(const float4*)(W2 + (size_t)(nb + lr) * Dn + k0 + lk);
        const float4 w3 = *(const float4*)(W3 + (size_t)(nb + lr) * Dn + k0 + lk);
        __syncthreads();
        As[lk+0][lr] = a.x;  As[lk+1][lr] = a.y;  As[lk+2][lr] = a.z;  As[lk+3][lr] = a.w;
        Bs[0][lk+0][lr] = w0.x; Bs[0][lk+1][lr] = w0.y; Bs[0][lk+2][lr] = w0.z; Bs[0][lk+3][lr] = w0.w;
        Bs[1][lk+0][lr] = w1.x; Bs[1][lk+1][lr] = w1.y; Bs[1][lk+2][lr] = w1.z; Bs[1][lk+3][lr] = w1.w;
        Bs[2][lk+0][lr] = w2.x; Bs[2][lk+1][lr] = w2.y; Bs[2][lk+2][lr] = w2.z; Bs[2][lk+3][lr] = w2.w;
        Bs[3][lk+0][lr] = w3.x; Bs[3][lk+1][lr] = w3.y; Bs[3][lk+2][lr] = w3.z; Bs[3][lk+3][lr] = w3.w;
        __syncthreads();

        #pragma unroll
        for (int kk = 0; kk < 16; ++kk) {
            const float4 av = *(const float4*)&As[kk][ty * 4];
            const float aa[4] = {av.x, av.y, av.z, av.w};
            #pragma unroll
            for (int m = 0; m < 4; ++m) {
                const float4 bv = *(const float4*)&Bs[m][kk][tx * 4];
                const float bb[4] = {bv.x, bv.y, bv.z, bv.w};
                #pragma unroll
                for (int i = 0; i < 4; ++i)
                    #pragma unroll
                    for (int j = 0; j < 4; ++j)
                        acc[m][i][j] = fmaf(aa[i], bb[j], acc[m][i][j]);
            }
        }
    }

    const float4 bb0 = *(const float4*)(b0 + nb + tx * 4);
    const float4 bb1 = *(const float4*)(b1 + nb + tx * 4);
    const float4 bb2 = *(const float4*)(b2 + nb + tx * 4);
    const float4 bb3 = *(const float4*)(b3 + nb + tx * 4);

    #pragma unroll
    for (int i = 0; i < 4; ++i) {
        const size_t rowoff = (size_t)(mb + ty * 4 + i) * Dn + nb + tx * 4;
        float4 o;
        o.x = acc[0][i][0] + bb0.x; o.y = acc[0][i][1] + bb0.y;
        o.z = acc[0][i][2] + bb0.z; o.w = acc[0][i][3] + bb0.w;
        *(float4*)(Y0 + rowoff) = o;
        o.x = acc[1][i][0] + bb1.x; o.y = acc[1][i][1] + bb1.y;
        o.z = acc[1][i][2] + bb1.z; o.w = acc[1][i][3] + bb1.w;
        *(float4*)(Y1 + rowoff) = o;
        o.x = sigmoidf_(acc[2][i][0] + bb2.x); o.y = sigmoidf_(acc[2][i][1] + bb2.y);
        o.z = sigmoidf_(acc[2][i][2] + bb2.z); o.w = sigmoidf_(acc[2][i][3] + bb2.w);
        *(float4*)(Y2 + rowoff) = o;
        o.x = __expf(acc[3][i][0] + bb3.x); o.y = __expf(acc[3][i][1] + bb3.y);
        o.z = __expf(acc[3][i][2] + bb3.z); o.w = __expf(acc[3][i][3] + bb3.w);
        *(float4*)(Y3 + rowoff) = o;
    }
}

// ---------------------------------------------------------------------------
// Output GEMM: out = (num * invden) @ Wo^T + bo  (invden folded into A-load)
// ---------------------------------------------------------------------------
__global__ __launch_bounds__(256) void out_gemm(
    const float* __restrict__ X, const float* __restrict__ W,
    const float* __restrict__ bias, float* __restrict__ Y)
{
    __shared__ float As[16][68];
    __shared__ float Bs[16][68];

    const int tid = threadIdx.x;
    const int tx = tid & 15;
    const int ty = tid >> 4;
    const int mb = blockIdx.x * 64;
    const int nb = blockIdx.y * 64;
    const int lr = tid >> 2;
    const int lk = (tid & 3) * 4;

    const float dn   = g_den[mb + lr];
    const float invd = 1.0f / fmaxf(fabsf(dn), 1.0f);

    float acc[4][4];
    #pragma unroll
    for (int i = 0; i < 4; ++i)
        #pragma unroll
        for (int j = 0; j < 4; ++j) acc[i][j] = 0.0f;

    for (int k0 = 0; k0 < Dn; k0 += 16) {
        float4 a = *(const float4*)(X + (size_t)(mb + lr) * Dn + k0 + lk);
        const float4 w = *(const float4*)(W + (size_t)(nb + lr) * Dn + k0 + lk);
        a.x *= invd; a.y *= invd; a.z *= invd; a.w *= invd;
        __syncthreads();
        As[lk+0][lr] = a.x; As[lk+1][lr] = a.y; As[lk+2][lr] = a.z; As[lk+3][lr] = a.w;
        Bs[lk+0][lr] = w.x; Bs[lk+1][lr] = w.y; Bs[lk+2][lr] = w.z; Bs[lk+3][lr] = w.w;
        __syncthreads();

        #pragma unroll
        for (int kk = 0; kk < 16; ++kk) {
            const float4 av = *(const float4*)&As[kk][ty * 4];
            const float4 bv = *(const float4*)&Bs[kk][tx * 4];
            const float aa[4] = {av.x, av.y, av.z, av.w};
            const float bb[4] = {bv.x, bv.y, bv.z, bv.w};
            #pragma unroll
            for (int i = 0; i < 4; ++i)
                #pragma unroll
                for (int j = 0; j < 4; ++j)
                    acc[i][j] = fmaf(aa[i], bb[j], acc[i][j]);
        }
    }

    const float4 bbv = *(const float4*)(bias + nb + tx * 4);
    #pragma unroll
    for (int i = 0; i < 4; ++i) {
        const size_t rowoff = (size_t)(mb + ty * 4 + i) * Dn + nb + tx * 4;
        float4 o;
        o.x = acc[i][0] + bbv.x; o.y = acc[i][1] + bbv.y;
        o.z = acc[i][2] + bbv.z; o.w = acc[i][3] + bbv.w;
        *(float4*)(Y + rowoff) = o;
    }
}

// ---------------------------------------------------------------------------
// Pass 1: per-segment summaries. Grid (NS, 33, B).
//  gx<32 : U_seg (8 rows x 256) via U = f⊙U + (i*v)⊙k^T from zero; A_end[r]=Πf.
//  gx==32: u_n = f⊙u + i⊙k from zero; a_n = Πf (elementwise, 256 dims).
// ---------------------------------------------------------------------------
__global__ __launch_bounds__(256) void seg_summary(
    const float* __restrict__ Pf, const float* __restrict__ Pi,
    const float* __restrict__ Pk, const float* __restrict__ Pq,
    float* __restrict__ U, float* __restrict__ Aend,
    float* __restrict__ un, float* __restrict__ an)
{
    const int m  = blockIdx.x;
    const int gx = blockIdx.y;
    const int b  = blockIdx.z;
    const size_t base = (size_t)b * Sn * Dn + (size_t)m * LS * Dn;
    const int tid = threadIdx.x;

    if (gx == 32) {
        const int c = tid;
        float u = 0.0f, a = 1.0f;
        #pragma unroll 4
        for (int t = 0; t < LS; ++t) {
            const size_t off = base + (size_t)t * Dn + c;
            const float f  = Pf[off];
            const float iv = Pi[off];
            const float kv = Pk[off];
            u = fmaf(f, u, iv * kv);
            a *= f;
        }
        const size_t s = ((size_t)b * NS + m) * Dn + c;
        un[s] = u;
        an[s] = a;
        return;
    }

    const int lane = tid & 63;
    const int w    = tid >> 6;
    const int r0   = gx * 8 + w * 2;
    const int c0   = lane * 4;

    float U00=0.f,U01=0.f,U02=0.f,U03=0.f;
    float U10=0.f,U11=0.f,U12=0.f,U13=0.f;
    float a0 = 1.0f, a1 = 1.0f;

    #pragma unroll 4
    for (int t = 0; t < LS; ++t) {
        const size_t off = base + (size_t)t * Dn;
        const float4 k4 = *(const float4*)(Pk + off + c0);
        const float2 fr = *(const float2*)(Pf + off + r0);
        const float2 ir = *(const float2*)(Pi + off + r0);
        const float2 vr = *(const float2*)(Pq + off + r0);   // v = q projection
        const float w0 = ir.x * vr.x;
        const float w1 = ir.y * vr.y;
        U00 = fmaf(fr.x, U00, w0 * k4.x);
        U01 = fmaf(fr.x, U01, w0 * k4.y);
        U02 = fmaf(fr.x, U02, w0 * k4.z);
        U03 = fmaf(fr.x, U03, w0 * k4.w);
        U10 = fmaf(fr.y, U10, w1 * k4.x);
        U11 = fmaf(fr.y, U11, w1 * k4.y);
        U12 = fmaf(fr.y, U12, w1 * k4.z);
        U13 = fmaf(fr.y, U13, w1 * k4.w);
        a0 *= fr.x;
        a1 *= fr.y;
    }

    float* Ub = U + (((size_t)b * NS + m) * Dn + r0) * Dn + c0;
    *(float4*)Ub        = make_float4(U00, U01, U02, U03);
    *(float4*)(Ub + Dn) = make_float4(U10, U11, U12, U13);
    if (lane < 2)
        Aend[((size_t)b * NS + m) * Dn + r0 + lane] = (lane == 0 ? a0 : a1);
}

// ---------------------------------------------------------------------------
// Pass 2: per-segment scan with composed carry-in. Grid (NS, 33, B).
//  gx<32 : C_in = Σ_{j<m} (Π_{l∈(j,m)} A_l)⊙U_j, then 64-step scan -> Pnum.
//  gx==32: n_in likewise from (u_n,a_n), then den scan -> g_den.
// ---------------------------------------------------------------------------
__global__ __launch_bounds__(256) void seg_scan(
    const float* __restrict__ Pf, const float* __restrict__ Pi,
    const float* __restrict__ Pk, const float* __restrict__ Pq,
    const float* __restrict__ U, const float* __restrict__ Aend,
    const float* __restrict__ un, const float* __restrict__ an,
    float* __restrict__ Pnum)
{
    __shared__ float dpart[4][16];

    const int m  = blockIdx.x;
    const int gx = blockIdx.y;
    const int b  = blockIdx.z;
    const size_t base = (size_t)b * Sn * Dn + (size_t)m * LS * Dn;
    const int tid  = threadIdx.x;
    const int lane = tid & 63;
    const int w    = tid >> 6;

    if (gx == 32) {
        const int c = tid;
        float n = 0.0f, d = 1.0f;
        for (int j = m - 1; j >= 0; --j) {
            const size_t sj = ((size_t)b * NS + j) * Dn + c;
            n = fmaf(d, un[sj], n);
            d *= an[sj];
        }
        for (int t0 = 0; t0 < LS; t0 += 16) {
            float p[16];
            #pragma unroll
            for (int j = 0; j < 16; ++j) {
                const size_t off = base + (size_t)(t0 + j) * Dn + c;
                n = fmaf(Pf[off], n, Pi[off] * Pk[off]);
                p[j] = n * Pq[off];
            }
            #pragma unroll
            for (int s = 1; s < 64; s <<= 1)
                #pragma unroll
                for (int j = 0; j < 16; ++j)
                    p[j] += __shfl_xor(p[j], s, 64);
            if (lane == 0) {
                #pragma unroll
                for (int j = 0; j < 16; ++j) dpart[w][j] = p[j];
            }
            __syncthreads();
            if (tid < 16)
                g_den[b * Sn + m * LS + t0 + tid] =
                    dpart[0][tid] + dpart[1][tid] + dpart[2][tid] + dpart[3][tid];
            __syncthreads();
        }
        return;
    }

    const int r0 = gx * 8 + w * 2;
    const int c0 = lane * 4;

    // ---- compose carry-in state ----
    float C00=0.f,C01=0.f,C02=0.f,C03=0.f;
    float C10=0.f,C11=0.f,C12=0.f,C13=0.f;
    float d0 = 1.0f, d1 = 1.0f;
    for (int j = m - 1; j >= 0; --j) {
        const float* Ub = U + (((size_t)b * NS + j) * Dn + r0) * Dn + c0;
        const float4 u0 = *(const float4*)Ub;
        const float4 u1 = *(const float4*)(Ub + Dn);
        C00 = fmaf(d0, u0.x, C00); C01 = fmaf(d0, u0.y, C01);
        C02 = fmaf(d0, u0.z, C02); C03 = fmaf(d0, u0.w, C03);
        C10 = fmaf(d1, u1.x, C10); C11 = fmaf(d1, u1.y, C11);
        C12 = fmaf(d1, u1.z, C12); C13 = fmaf(d1, u1.w, C13);
        const size_t sj = ((size_t)b * NS + j) * Dn + r0;
        d0 *= Aend[sj];
        d1 *= Aend[sj + 1];
    }

    // ---- 64-step scan (proven r2 structure) ----
    float* pnum = Pnum + base;
    for (int t0 = 0; t0 < LS; t0 += 8) {
        float m0[8], m1[8];
        #pragma unroll
        for (int j = 0; j < 8; ++j) {
            const size_t off = base + (size_t)(t0 + j) * Dn;
            const float4 k4 = *(const float4*)(Pk + off + c0);
            const float4 q4 = *(const float4*)(Pq + off + c0);
            const float2 fr = *(const float2*)(Pf + off + r0);
            const float2 ir = *(const float2*)(Pi + off + r0);
            const float2 vr = *(const float2*)(Pq + off + r0);   // v = q proj

            const float w0 = ir.x * vr.x;
            const float w1 = ir.y * vr.y;
            C00 = fmaf(fr.x, C00, w0 * k4.x);
            C01 = fmaf(fr.x, C01, w0 * k4.y);
            C02 = fmaf(fr.x, C02, w0 * k4.z);
            C03 = fmaf(fr.x, C03, w0 * k4.w);
            C10 = fmaf(fr.y, C10, w1 * k4.x);
            C11 = fmaf(fr.y, C11, w1 * k4.y);
            C12 = fmaf(fr.y, C12, w1 * k4.z);
            C13 = fmaf(fr.y, C13, w1 * k4.w);

            float a0 = C00 * q4.x;
            a0 = fmaf(C01, q4.y, a0);
            a0 = fmaf(C02, q4.z, a0);
            a0 = fmaf(C03, q4.w, a0);
            float a1 = C10 * q4.x;
            a1 = fmaf(C11, q4.y, a1);
            a1 = fmaf(C12, q4.z, a1);
            a1 = fmaf(C13, q4.w, a1);
            m0[j] = a0;
            m1[j] = a1;
        }

        #pragma unroll
        for (int s = 1; s < 64; s <<= 1) {
            #pragma unroll
            for (int j = 0; j < 8; ++j) {
                m0[j] += __shfl_xor(m0[j], s, 64);
                m1[j] += __shfl_xor(m1[j], s, 64);
            }
        }

        if (lane < 2) {
            #pragma unroll
            for (int j = 0; j < 8; ++j)
                pnum[(size_t)(t0 + j) * Dn + r0 + lane] = (lane == 0 ? m0[j] : m1[j]);
        }
    }
}

} // anonymous namespace

extern "C" void kernel_launch(void* const* d_in, const int* in_sizes, int n_in,
                              void* d_out, int out_size, void* d_ws, size_t ws_size,
                              hipStream_t stream)
{
    const float* x  = (const float*)d_in[0];
    const float* Wq = (const float*)d_in[1];  const float* bq = (const float*)d_in[2];
    const float* Wk = (const float*)d_in[3];  const float* bk = (const float*)d_in[4];
    // d_in[5]=Wv, d_in[6]=bv unused (reference uses W_q for v)
    const float* Wf = (const float*)d_in[7];  const float* bf = (const float*)d_in[8];
    const float* Wi = (const float*)d_in[9];  const float* bi = (const float*)d_in[10];
    const float* Wo = (const float*)d_in[11]; const float* bo = (const float*)d_in[12];
    float* out = (float*)d_out;

    float* ws = (float*)d_ws;
    const size_t sz = (size_t)Mn * Dn;           // 2,097,152 floats (8 MB)
    float* Pq = ws;
    float* Pk = ws + sz;
    float* Pf = ws + 2 * sz;
    float* Pi = ws + 3 * sz;
    float* Pn = ws + 4 * sz;                     // raw numerators
    float* U    = ws + 5 * sz;                   // [B][NS][D][D] = 32 MB
    float* Aend = U + (size_t)Bn * NS * Dn * Dn; // [B][NS][D]
    float* un   = Aend + (size_t)Bn * NS * Dn;   // [B][NS][D]
    float* an   = un   + (size_t)Bn * NS * Dn;   // [B][NS][D]

    proj_gemm<<<dim3(Mn / 64, Dn / 64), 256, 0, stream>>>(
        x, Wq, bq, Wk, bk, Wf, bf, Wi, bi, Pq, Pk, Pf, Pi);

    seg_summary<<<dim3(NS, 33, Bn), 256, 0, stream>>>(
        Pf, Pi, Pk, Pq, U, Aend, un, an);

    seg_scan<<<dim3(NS, 33, Bn), 256, 0, stream>>>(
        Pf, Pi, Pk, Pq, U, Aend, un, an, Pn);

    out_gemm<<<dim3(Mn / 64, Dn / 64), 256, 0, stream>>>(Pn, Wo, bo, out);
}

// Round 6
// 397.614 us; speedup vs baseline: 1.4447x; 1.1772x over previous
//
#include <hip/hip_runtime.h>
#include <math.h>

namespace {

constexpr int Bn = 8;
constexpr int Sn = 1024;
constexpr int Dn = 256;
constexpr int Mn = Bn * Sn;    // 8192 rows
constexpr int NS = 16;         // time segments
constexpr int LS = Sn / NS;    // 64 steps per segment

__device__ float g_den[Bn * Sn];   // raw n·q per (b,t); clamp applied in out_gemm

__device__ __forceinline__ float sigmoidf_(float x) {
    return 1.0f / (1.0f + __expf(-x));
}

// ---------------------------------------------------------------------------
// Fused projection GEMM: Y_m = act_m(X @ W_m^T + b_m) for m in {q,k,f,i}
// ---------------------------------------------------------------------------
__global__ __launch_bounds__(256) void proj_gemm(
    const float* __restrict__ X,
    const float* __restrict__ W0, const float* __restrict__ b0,
    const float* __restrict__ W1, const float* __restrict__ b1,
    const float* __restrict__ W2, const float* __restrict__ b2,
    const float* __restrict__ W3, const float* __restrict__ b3,
    float* __restrict__ Y0, float* __restrict__ Y1,
    float* __restrict__ Y2, float* __restrict__ Y3)
{
    __shared__ float As[16][68];
    __shared__ float Bs[4][16][68];

    const int tid = threadIdx.x;
    const int tx = tid & 15;
    const int ty = tid >> 4;
    const int mb = blockIdx.x * 64;
    const int nb = blockIdx.y * 64;
    const int lr = tid >> 2;
    const int lk = (tid & 3) * 4;

    float acc[4][4][4];
    #pragma unroll
    for (int m = 0; m < 4; ++m)
        #pragma unroll
        for (int i = 0; i < 4; ++i)
            #pragma unroll
            for (int j = 0; j < 4; ++j) acc[m][i][j] = 0.0f;

    for (int k0 = 0; k0 < Dn; k0 += 16) {
        const float4 a  = *(const float4*)(X  + (size_t)(mb + lr) * Dn + k0 + lk);
        const float4 w0 = *(const float4*)(W0 + (size_t)(nb + lr) * Dn + k0 + lk);
        const float4 w1 = *(const float4*)(W1 + (size_t)(nb + lr) * Dn + k0 + lk);
        const float4 w2 = *(const float4*)(W2 + (size_t)(nb + lr) * Dn + k0 + lk);
        const float4 w3 = *(const float4*)(W3 + (size_t)(nb + lr) * Dn + k0 + lk);
        __syncthreads();
        As[lk+0][lr] = a.x;  As[lk+1][lr] = a.y;  As[lk+2][lr] = a.z;  As[lk+3][lr] = a.w;
        Bs[0][lk+0][lr] = w0.x; Bs[0][lk+1][lr] = w0.y; Bs[0][lk+2][lr] = w0.z; Bs[0][lk+3][lr] = w0.w;
        Bs[1][lk+0][lr] = w1.x; Bs[1][lk+1][lr] = w1.y; Bs[1][lk+2][lr] = w1.z; Bs[1][lk+3][lr] = w1.w;
        Bs[2][lk+0][lr] = w2.x; Bs[2][lk+1][lr] = w2.y; Bs[2][lk+2][lr] = w2.z; Bs[2][lk+3][lr] = w2.w;
        Bs[3][lk+0][lr] = w3.x; Bs[3][lk+1][lr] = w3.y; Bs[3][lk+2][lr] = w3.z; Bs[3][lk+3][lr] = w3.w;
        __syncthreads();

        #pragma unroll
        for (int kk = 0; kk < 16; ++kk) {
            const float4 av = *(const float4*)&As[kk][ty * 4];
            const float aa[4] = {av.x, av.y, av.z, av.w};
            #pragma unroll
            for (int m = 0; m < 4; ++m) {
                const float4 bv = *(const float4*)&Bs[m][kk][tx * 4];
                const float bb[4] = {bv.x, bv.y, bv.z, bv.w};
                #pragma unroll
                for (int i = 0; i < 4; ++i)
                    #pragma unroll
                    for (int j = 0; j < 4; ++j)
                        acc[m][i][j] = fmaf(aa[i], bb[j], acc[m][i][j]);
            }
        }
    }

    const float4 bb0 = *(const float4*)(b0 + nb + tx * 4);
    const float4 bb1 = *(const float4*)(b1 + nb + tx * 4);
    const float4 bb2 = *(const float4*)(b2 + nb + tx * 4);
    const float4 bb3 = *(const float4*)(b3 + nb + tx * 4);

    #pragma unroll
    for (int i = 0; i < 4; ++i) {
        const size_t rowoff = (size_t)(mb + ty * 4 + i) * Dn + nb + tx * 4;
        float4 o;
        o.x = acc[0][i][0] + bb0.x; o.y = acc[0][i][1] + bb0.y;
        o.z = acc[0][i][2] + bb0.z; o.w = acc[0][i][3] + bb0.w;
        *(float4*)(Y0 + rowoff) = o;
        o.x = acc[1][i][0] + bb1.x; o.y = acc[1][i][1] + bb1.y;
        o.z = acc[1][i][2] + bb1.z; o.w = acc[1][i][3] + bb1.w;
        *(float4*)(Y1 + rowoff) = o;
        o.x = sigmoidf_(acc[2][i][0] + bb2.x); o.y = sigmoidf_(acc[2][i][1] + bb2.y);
        o.z = sigmoidf_(acc[2][i][2] + bb2.z); o.w = sigmoidf_(acc[2][i][3] + bb2.w);
        *(float4*)(Y2 + rowoff) = o;
        o.x = __expf(acc[3][i][0] + bb3.x); o.y = __expf(acc[3][i][1] + bb3.y);
        o.z = __expf(acc[3][i][2] + bb3.z); o.w = __expf(acc[3][i][3] + bb3.w);
        *(float4*)(Y3 + rowoff) = o;
    }
}

// ---------------------------------------------------------------------------
// Output GEMM: out = (num * invden) @ Wo^T + bo  (invden folded into A-load)
// ---------------------------------------------------------------------------
__global__ __launch_bounds__(256) void out_gemm(
    const float* __restrict__ X, const float* __restrict__ W,
    const float* __restrict__ bias, float* __restrict__ Y)
{
    __shared__ float As[16][68];
    __shared__ float Bs[16][68];

    const int tid = threadIdx.x;
    const int tx = tid & 15;
    const int ty = tid >> 4;
    const int mb = blockIdx.x * 64;
    const int nb = blockIdx.y * 64;
    const int lr = tid >> 2;
    const int lk = (tid & 3) * 4;

    const float dn   = g_den[mb + lr];
    const float invd = 1.0f / fmaxf(fabsf(dn), 1.0f);

    float acc[4][4];
    #pragma unroll
    for (int i = 0; i < 4; ++i)
        #pragma unroll
        for (int j = 0; j < 4; ++j) acc[i][j] = 0.0f;

    for (int k0 = 0; k0 < Dn; k0 += 16) {
        float4 a = *(const float4*)(X + (size_t)(mb + lr) * Dn + k0 + lk);
        const float4 w = *(const float4*)(W + (size_t)(nb + lr) * Dn + k0 + lk);
        a.x *= invd; a.y *= invd; a.z *= invd; a.w *= invd;
        __syncthreads();
        As[lk+0][lr] = a.x; As[lk+1][lr] = a.y; As[lk+2][lr] = a.z; As[lk+3][lr] = a.w;
        Bs[lk+0][lr] = w.x; Bs[lk+1][lr] = w.y; Bs[lk+2][lr] = w.z; Bs[lk+3][lr] = w.w;
        __syncthreads();

        #pragma unroll
        for (int kk = 0; kk < 16; ++kk) {
            const float4 av = *(const float4*)&As[kk][ty * 4];
            const float4 bv = *(const float4*)&Bs[kk][tx * 4];
            const float aa[4] = {av.x, av.y, av.z, av.w};
            const float bb[4] = {bv.x, bv.y, bv.z, bv.w};
            #pragma unroll
            for (int i = 0; i < 4; ++i)
                #pragma unroll
                for (int j = 0; j < 4; ++j)
                    acc[i][j] = fmaf(aa[i], bb[j], acc[i][j]);
        }
    }

    const float4 bbv = *(const float4*)(bias + nb + tx * 4);
    #pragma unroll
    for (int i = 0; i < 4; ++i) {
        const size_t rowoff = (size_t)(mb + ty * 4 + i) * Dn + nb + tx * 4;
        float4 o;
        o.x = acc[i][0] + bbv.x; o.y = acc[i][1] + bbv.y;
        o.z = acc[i][2] + bbv.z; o.w = acc[i][3] + bbv.w;
        *(float4*)(Y + rowoff) = o;
    }
}

// ---------------------------------------------------------------------------
// Pass 1: per-segment summaries. Grid (NS, 17, B). 16 rows/block (4/wave).
//  gx<16 : U_seg (16 rows x 256) + A_end[r] = Π f.
//  gx==16: u_n = f⊙u + i⊙k from zero; a_n = Πf (elementwise, 256 dims).
// ---------------------------------------------------------------------------
__global__ __launch_bounds__(256) void seg_summary(
    const float* __restrict__ Pf, const float* __restrict__ Pi,
    const float* __restrict__ Pk, const float* __restrict__ Pq,
    float* __restrict__ U, float* __restrict__ Aend,
    float* __restrict__ un, float* __restrict__ an)
{
    const int m  = blockIdx.x;
    const int gx = blockIdx.y;
    const int b  = blockIdx.z;
    const size_t base = (size_t)b * Sn * Dn + (size_t)m * LS * Dn;
    const int tid = threadIdx.x;

    if (gx == 16) {
        const int c = tid;
        float u = 0.0f, a = 1.0f;
        #pragma unroll 4
        for (int t = 0; t < LS; ++t) {
            const size_t off = base + (size_t)t * Dn + c;
            const float f  = Pf[off];
            const float iv = Pi[off];
            const float kv = Pk[off];
            u = fmaf(f, u, iv * kv);
            a *= f;
        }
        const size_t s = ((size_t)b * NS + m) * Dn + c;
        un[s] = u;
        an[s] = a;
        return;
    }

    const int lane = tid & 63;
    const int w    = tid >> 6;
    const int r0   = gx * 16 + w * 4;   // 4 rows per wave
    const int c0   = lane * 4;

    float C0[4] = {0,0,0,0}, C1[4] = {0,0,0,0}, C2[4] = {0,0,0,0}, C3[4] = {0,0,0,0};
    float a0 = 1.f, a1 = 1.f, a2 = 1.f, a3 = 1.f;

    #pragma unroll 4
    for (int t = 0; t < LS; ++t) {
        const size_t off = base + (size_t)t * Dn;
        const float4 k4 = *(const float4*)(Pk + off + c0);
        const float4 fr = *(const float4*)(Pf + off + r0);
        const float4 ir = *(const float4*)(Pi + off + r0);
        const float4 vr = *(const float4*)(Pq + off + r0);   // v = q projection
        const float w0 = ir.x * vr.x;
        const float w1 = ir.y * vr.y;
        const float w2 = ir.z * vr.z;
        const float w3 = ir.w * vr.w;
        C0[0] = fmaf(fr.x, C0[0], w0 * k4.x); C0[1] = fmaf(fr.x, C0[1], w0 * k4.y);
        C0[2] = fmaf(fr.x, C0[2], w0 * k4.z); C0[3] = fmaf(fr.x, C0[3], w0 * k4.w);
        C1[0] = fmaf(fr.y, C1[0], w1 * k4.x); C1[1] = fmaf(fr.y, C1[1], w1 * k4.y);
        C1[2] = fmaf(fr.y, C1[2], w1 * k4.z); C1[3] = fmaf(fr.y, C1[3], w1 * k4.w);
        C2[0] = fmaf(fr.z, C2[0], w2 * k4.x); C2[1] = fmaf(fr.z, C2[1], w2 * k4.y);
        C2[2] = fmaf(fr.z, C2[2], w2 * k4.z); C2[3] = fmaf(fr.z, C2[3], w2 * k4.w);
        C3[0] = fmaf(fr.w, C3[0], w3 * k4.x); C3[1] = fmaf(fr.w, C3[1], w3 * k4.y);
        C3[2] = fmaf(fr.w, C3[2], w3 * k4.z); C3[3] = fmaf(fr.w, C3[3], w3 * k4.w);
        a0 *= fr.x; a1 *= fr.y; a2 *= fr.z; a3 *= fr.w;
    }

    float* Ub = U + (((size_t)b * NS + m) * Dn + r0) * Dn + c0;
    *(float4*)(Ub + 0 * Dn) = make_float4(C0[0], C0[1], C0[2], C0[3]);
    *(float4*)(Ub + 1 * Dn) = make_float4(C1[0], C1[1], C1[2], C1[3]);
    *(float4*)(Ub + 2 * Dn) = make_float4(C2[0], C2[1], C2[2], C2[3]);
    *(float4*)(Ub + 3 * Dn) = make_float4(C3[0], C3[1], C3[2], C3[3]);
    if (lane < 4) {
        const float av = (lane == 0) ? a0 : (lane == 1) ? a1 : (lane == 2) ? a2 : a3;
        Aend[((size_t)b * NS + m) * Dn + r0 + lane] = av;
    }
}

// ---------------------------------------------------------------------------
// Pass 2: per-segment scan with composed carry-in. Grid (NS, 17, B).
// 16 rows/block (4/wave). gx==16: denominator duty.
// ---------------------------------------------------------------------------
__global__ __launch_bounds__(256) void seg_scan(
    const float* __restrict__ Pf, const float* __restrict__ Pi,
    const float* __restrict__ Pk, const float* __restrict__ Pq,
    const float* __restrict__ U, const float* __restrict__ Aend,
    const float* __restrict__ un, const float* __restrict__ an,
    float* __restrict__ Pnum)
{
    __shared__ float dpart[4][16];

    const int m  = blockIdx.x;
    const int gx = blockIdx.y;
    const int b  = blockIdx.z;
    const size_t base = (size_t)b * Sn * Dn + (size_t)m * LS * Dn;
    const int tid  = threadIdx.x;
    const int lane = tid & 63;
    const int w    = tid >> 6;

    if (gx == 16) {
        const int c = tid;
        float n = 0.0f, d = 1.0f;
        for (int j = m - 1; j >= 0; --j) {
            const size_t sj = ((size_t)b * NS + j) * Dn + c;
            n = fmaf(d, un[sj], n);
            d *= an[sj];
        }
        for (int t0 = 0; t0 < LS; t0 += 16) {
            float p[16];
            #pragma unroll
            for (int j = 0; j < 16; ++j) {
                const size_t off = base + (size_t)(t0 + j) * Dn + c;
                n = fmaf(Pf[off], n, Pi[off] * Pk[off]);
                p[j] = n * Pq[off];
            }
            #pragma unroll
            for (int s = 1; s < 64; s <<= 1)
                #pragma unroll
                for (int j = 0; j < 16; ++j)
                    p[j] += __shfl_xor(p[j], s, 64);
            if (lane == 0) {
                #pragma unroll
                for (int j = 0; j < 16; ++j) dpart[w][j] = p[j];
            }
            __syncthreads();
            if (tid < 16)
                g_den[b * Sn + m * LS + t0 + tid] =
                    dpart[0][tid] + dpart[1][tid] + dpart[2][tid] + dpart[3][tid];
            __syncthreads();
        }
        return;
    }

    const int r0 = gx * 16 + w * 4;   // 4 rows per wave
    const int c0 = lane * 4;

    // ---- compose carry-in state ----
    float C0[4] = {0,0,0,0}, C1[4] = {0,0,0,0}, C2[4] = {0,0,0,0}, C3[4] = {0,0,0,0};
    float d0 = 1.f, d1 = 1.f, d2 = 1.f, d3 = 1.f;
    for (int j = m - 1; j >= 0; --j) {
        const float* Ub = U + (((size_t)b * NS + j) * Dn + r0) * Dn + c0;
        const float4 u0 = *(const float4*)(Ub + 0 * Dn);
        const float4 u1 = *(const float4*)(Ub + 1 * Dn);
        const float4 u2 = *(const float4*)(Ub + 2 * Dn);
        const float4 u3 = *(const float4*)(Ub + 3 * Dn);
        C0[0] = fmaf(d0, u0.x, C0[0]); C0[1] = fmaf(d0, u0.y, C0[1]);
        C0[2] = fmaf(d0, u0.z, C0[2]); C0[3] = fmaf(d0, u0.w, C0[3]);
        C1[0] = fmaf(d1, u1.x, C1[0]); C1[1] = fmaf(d1, u1.y, C1[1]);
        C1[2] = fmaf(d1, u1.z, C1[2]); C1[3] = fmaf(d1, u1.w, C1[3]);
        C2[0] = fmaf(d2, u2.x, C2[0]); C2[1] = fmaf(d2, u2.y, C2[1]);
        C2[2] = fmaf(d2, u2.z, C2[2]); C2[3] = fmaf(d2, u2.w, C2[3]);
        C3[0] = fmaf(d3, u3.x, C3[0]); C3[1] = fmaf(d3, u3.y, C3[1]);
        C3[2] = fmaf(d3, u3.z, C3[2]); C3[3] = fmaf(d3, u3.w, C3[3]);
        const size_t sj = ((size_t)b * NS + j) * Dn + r0;
        d0 *= Aend[sj]; d1 *= Aend[sj + 1]; d2 *= Aend[sj + 2]; d3 *= Aend[sj + 3];
    }

    // ---- 64-step scan, reductions batched 8 deep (32 chains/wave) ----
    float* pnum = Pnum + base;
    for (int t0 = 0; t0 < LS; t0 += 8) {
        float m0[8], m1[8], m2[8], m3[8];
        #pragma unroll
        for (int j = 0; j < 8; ++j) {
            const size_t off = base + (size_t)(t0 + j) * Dn;
            const float4 k4 = *(const float4*)(Pk + off + c0);
            const float4 q4 = *(const float4*)(Pq + off + c0);
            const float4 fr = *(const float4*)(Pf + off + r0);
            const float4 ir = *(const float4*)(Pi + off + r0);
            const float4 vr = *(const float4*)(Pq + off + r0);   // v = q proj

            const float w0 = ir.x * vr.x;
            const float w1 = ir.y * vr.y;
            const float w2 = ir.z * vr.z;
            const float w3 = ir.w * vr.w;
            C0[0] = fmaf(fr.x, C0[0], w0 * k4.x); C0[1] = fmaf(fr.x, C0[1], w0 * k4.y);
            C0[2] = fmaf(fr.x, C0[2], w0 * k4.z); C0[3] = fmaf(fr.x, C0[3], w0 * k4.w);
            C1[0] = fmaf(fr.y, C1[0], w1 * k4.x); C1[1] = fmaf(fr.y, C1[1], w1 * k4.y);
            C1[2] = fmaf(fr.y, C1[2], w1 * k4.z); C1[3] = fmaf(fr.y, C1[3], w1 * k4.w);
            C2[0] = fmaf(fr.z, C2[0], w2 * k4.x); C2[1] = fmaf(fr.z, C2[1], w2 * k4.y);
            C2[2] = fmaf(fr.z, C2[2], w2 * k4.z); C2[3] = fmaf(fr.z, C2[3], w2 * k4.w);
            C3[0] = fmaf(fr.w, C3[0], w3 * k4.x); C3[1] = fmaf(fr.w, C3[1], w3 * k4.y);
            C3[2] = fmaf(fr.w, C3[2], w3 * k4.z); C3[3] = fmaf(fr.w, C3[3], w3 * k4.w);

            float a0 = C0[0] * q4.x; a0 = fmaf(C0[1], q4.y, a0);
            a0 = fmaf(C0[2], q4.z, a0); a0 = fmaf(C0[3], q4.w, a0);
            float a1 = C1[0] * q4.x; a1 = fmaf(C1[1], q4.y, a1);
            a1 = fmaf(C1[2], q4.z, a1); a1 = fmaf(C1[3], q4.w, a1);
            float a2 = C2[0] * q4.x; a2 = fmaf(C2[1], q4.y, a2);
            a2 = fmaf(C2[2], q4.z, a2); a2 = fmaf(C2[3], q4.w, a2);
            float a3 = C3[0] * q4.x; a3 = fmaf(C3[1], q4.y, a3);
            a3 = fmaf(C3[2], q4.z, a3); a3 = fmaf(C3[3], q4.w, a3);
            m0[j] = a0; m1[j] = a1; m2[j] = a2; m3[j] = a3;
        }

        #pragma unroll
        for (int s = 1; s < 64; s <<= 1) {
            #pragma unroll
            for (int j = 0; j < 8; ++j) {
                m0[j] += __shfl_xor(m0[j], s, 64);
                m1[j] += __shfl_xor(m1[j], s, 64);
                m2[j] += __shfl_xor(m2[j], s, 64);
                m3[j] += __shfl_xor(m3[j], s, 64);
            }
        }

        if (lane < 4) {
            #pragma unroll
            for (int j = 0; j < 8; ++j) {
                const float val = (lane == 0) ? m0[j] : (lane == 1) ? m1[j]
                                : (lane == 2) ? m2[j] : m3[j];
                pnum[(size_t)(t0 + j) * Dn + r0 + lane] = val;
            }
        }
    }
}

} // anonymous namespace

extern "C" void kernel_launch(void* const* d_in, const int* in_sizes, int n_in,
                              void* d_out, int out_size, void* d_ws, size_t ws_size,
                              hipStream_t stream)
{
    const float* x  = (const float*)d_in[0];
    const float* Wq = (const float*)d_in[1];  const float* bq = (const float*)d_in[2];
    const float* Wk = (const float*)d_in[3];  const float* bk = (const float*)d_in[4];
    // d_in[5]=Wv, d_in[6]=bv unused (reference uses W_q for v)
    const float* Wf = (const float*)d_in[7];  const float* bf = (const float*)d_in[8];
    const float* Wi = (const float*)d_in[9];  const float* bi = (const float*)d_in[10];
    const float* Wo = (const float*)d_in[11]; const float* bo = (const float*)d_in[12];
    float* out = (float*)d_out;

    float* ws = (float*)d_ws;
    const size_t sz = (size_t)Mn * Dn;           // 2,097,152 floats (8 MB)
    float* Pq = ws;
    float* Pk = ws + sz;
    float* Pf = ws + 2 * sz;
    float* Pi = ws + 3 * sz;
    float* Pn = ws + 4 * sz;                     // raw numerators
    float* U    = ws + 5 * sz;                   // [B][NS][D][D] = 32 MB
    float* Aend = U + (size_t)Bn * NS * Dn * Dn; // [B][NS][D]
    float* un   = Aend + (size_t)Bn * NS * Dn;   // [B][NS][D]
    float* an   = un   + (size_t)Bn * NS * Dn;   // [B][NS][D]

    proj_gemm<<<dim3(Mn / 64, Dn / 64), 256, 0, stream>>>(
        x, Wq, bq, Wk, bk, Wf, bf, Wi, bi, Pq, Pk, Pf, Pi);

    seg_summary<<<dim3(NS, 17, Bn), 256, 0, stream>>>(
        Pf, Pi, Pk, Pq, U, Aend, un, an);

    seg_scan<<<dim3(NS, 17, Bn), 256, 0, stream>>>(
        Pf, Pi, Pk, Pq, U, Aend, un, an, Pn);

    out_gemm<<<dim3(Mn / 64, Dn / 64), 256, 0, stream>>>(Pn, Wo, bo, out);
}

// Round 7
// 328.717 us; speedup vs baseline: 1.7475x; 1.2096x over previous
//
#include <hip/hip_runtime.h>
#include <math.h>

namespace {

constexpr int Bn = 8;
constexpr int Sn = 1024;
constexpr int Dn = 256;
constexpr int Mn = Bn * Sn;    // 8192 rows
constexpr int NS = 16;         // time segments
constexpr int LS = Sn / NS;    // 64 steps per segment

__device__ float g_den[Bn * Sn];   // raw n·q per (b,t); clamp applied in out_gemm

__device__ __forceinline__ float sigmoidf_(float x) {
    return 1.0f / (1.0f + __expf(-x));
}

// ---------------------------------------------------------------------------
// Multi-value split-butterfly reductions over 64 lanes.
// 32 values: 32 shfls (vs 192 naive). Result: lane L holds full sum of
// logical value id=(L>>1)&31 (duplicated on lane pairs).
// ---------------------------------------------------------------------------
__device__ __forceinline__ void multi_reduce32(float v[32], int lane) {
    {   const bool hi = (lane & 32) != 0;
        #pragma unroll
        for (int i = 0; i < 16; ++i) {
            const float send = hi ? v[i] : v[i + 16];
            const float recv = __shfl_xor(send, 32, 64);
            v[i] = (hi ? v[i + 16] : v[i]) + recv;
        } }
    {   const bool hi = (lane & 16) != 0;
        #pragma unroll
        for (int i = 0; i < 8; ++i) {
            const float send = hi ? v[i] : v[i + 8];
            const float recv = __shfl_xor(send, 16, 64);
            v[i] = (hi ? v[i + 8] : v[i]) + recv;
        } }
    {   const bool hi = (lane & 8) != 0;
        #pragma unroll
        for (int i = 0; i < 4; ++i) {
            const float send = hi ? v[i] : v[i + 4];
            const float recv = __shfl_xor(send, 8, 64);
            v[i] = (hi ? v[i + 4] : v[i]) + recv;
        } }
    {   const bool hi = (lane & 4) != 0;
        #pragma unroll
        for (int i = 0; i < 2; ++i) {
            const float send = hi ? v[i] : v[i + 2];
            const float recv = __shfl_xor(send, 4, 64);
            v[i] = (hi ? v[i + 2] : v[i]) + recv;
        } }
    {   const bool hi = (lane & 2) != 0;
        const float send = hi ? v[0] : v[1];
        const float recv = __shfl_xor(send, 2, 64);
        v[0] = (hi ? v[1] : v[0]) + recv;
    }
    v[0] += __shfl_xor(v[0], 1, 64);
}

// 16 values: 17 shfls. Lane L holds sum of id=(L>>2)&15 (lane quads).
__device__ __forceinline__ void multi_reduce16(float v[16], int lane) {
    {   const bool hi = (lane & 32) != 0;
        #pragma unroll
        for (int i = 0; i < 8; ++i) {
            const float send = hi ? v[i] : v[i + 8];
            const float recv = __shfl_xor(send, 32, 64);
            v[i] = (hi ? v[i + 8] : v[i]) + recv;
        } }
    {   const bool hi = (lane & 16) != 0;
        #pragma unroll
        for (int i = 0; i < 4; ++i) {
            const float send = hi ? v[i] : v[i + 4];
            const float recv = __shfl_xor(send, 16, 64);
            v[i] = (hi ? v[i + 4] : v[i]) + recv;
        } }
    {   const bool hi = (lane & 8) != 0;
        #pragma unroll
        for (int i = 0; i < 2; ++i) {
            const float send = hi ? v[i] : v[i + 2];
            const float recv = __shfl_xor(send, 8, 64);
            v[i] = (hi ? v[i + 2] : v[i]) + recv;
        } }
    {   const bool hi = (lane & 4) != 0;
        const float send = hi ? v[0] : v[1];
        const float recv = __shfl_xor(send, 4, 64);
        v[0] = (hi ? v[1] : v[0]) + recv;
    }
    v[0] += __shfl_xor(v[0], 2, 64);
    v[0] += __shfl_xor(v[0], 1, 64);
}

// ---------------------------------------------------------------------------
// Fused projection GEMM: Y_m = act_m(X @ W_m^T + b_m) for m in {q,k,f,i}
// ---------------------------------------------------------------------------
__global__ __launch_bounds__(256) void proj_gemm(
    const float* __restrict__ X,
    const float* __restrict__ W0, const float* __restrict__ b0,
    const float* __restrict__ W1, const float* __restrict__ b1,
    const float* __restrict__ W2, const float* __restrict__ b2,
    const float* __restrict__ W3, const float* __restrict__ b3,
    float* __restrict__ Y0, float* __restrict__ Y1,
    float* __restrict__ Y2, float* __restrict__ Y3)
{
    __shared__ float As[16][68];
    __shared__ float Bs[4][16][68];

    const int tid = threadIdx.x;
    const int tx = tid & 15;
    const int ty = tid >> 4;
    const int mb = blockIdx.x * 64;
    const int nb = blockIdx.y * 64;
    const int lr = tid >> 2;
    const int lk = (tid & 3) * 4;

    float acc[4][4][4];
    #pragma unroll
    for (int m = 0; m < 4; ++m)
        #pragma unroll
        for (int i = 0; i < 4; ++i)
            #pragma unroll
            for (int j = 0; j < 4; ++j) acc[m][i][j] = 0.0f;

    for (int k0 = 0; k0 < Dn; k0 += 16) {
        const float4 a  = *(const float4*)(X  + (size_t)(mb + lr) * Dn + k0 + lk);
        const float4 w0 = *(const float4*)(W0 + (size_t)(nb + lr) * Dn + k0 + lk);
        const float4 w1 = *(const float4*)(W1 + (size_t)(nb + lr) * Dn + k0 + lk);
        const float4 w2 = *(const float4*)(W2 + (size_t)(nb + lr) * Dn + k0 + lk);
        const float4 w3 = *(const float4*)(W3 + (size_t)(nb + lr) * Dn + k0 + lk);
        __syncthreads();
        As[lk+0][lr] = a.x;  As[lk+1][lr] = a.y;  As[lk+2][lr] = a.z;  As[lk+3][lr] = a.w;
        Bs[0][lk+0][lr] = w0.x; Bs[0][lk+1][lr] = w0.y; Bs[0][lk+2][lr] = w0.z; Bs[0][lk+3][lr] = w0.w;
        Bs[1][lk+0][lr] = w1.x; Bs[1][lk+1][lr] = w1.y; Bs[1][lk+2][lr] = w1.z; Bs[1][lk+3][lr] = w1.w;
        Bs[2][lk+0][lr] = w2.x; Bs[2][lk+1][lr] = w2.y; Bs[2][lk+2][lr] = w2.z; Bs[2][lk+3][lr] = w2.w;
        Bs[3][lk+0][lr] = w3.x; Bs[3][lk+1][lr] = w3.y; Bs[3][lk+2][lr] = w3.z; Bs[3][lk+3][lr] = w3.w;
        __syncthreads();

        #pragma unroll
        for (int kk = 0; kk < 16; ++kk) {
            const float4 av = *(const float4*)&As[kk][ty * 4];
            const float aa[4] = {av.x, av.y, av.z, av.w};
            #pragma unroll
            for (int m = 0; m < 4; ++m) {
                const float4 bv = *(const float4*)&Bs[m][kk][tx * 4];
                const float bb[4] = {bv.x, bv.y, bv.z, bv.w};
                #pragma unroll
                for (int i = 0; i < 4; ++i)
                    #pragma unroll
                    for (int j = 0; j < 4; ++j)
                        acc[m][i][j] = fmaf(aa[i], bb[j], acc[m][i][j]);
            }
        }
    }

    const float4 bb0 = *(const float4*)(b0 + nb + tx * 4);
    const float4 bb1 = *(const float4*)(b1 + nb + tx * 4);
    const float4 bb2 = *(const float4*)(b2 + nb + tx * 4);
    const float4 bb3 = *(const float4*)(b3 + nb + tx * 4);

    #pragma unroll
    for (int i = 0; i < 4; ++i) {
        const size_t rowoff = (size_t)(mb + ty * 4 + i) * Dn + nb + tx * 4;
        float4 o;
        o.x = acc[0][i][0] + bb0.x; o.y = acc[0][i][1] + bb0.y;
        o.z = acc[0][i][2] + bb0.z; o.w = acc[0][i][3] + bb0.w;
        *(float4*)(Y0 + rowoff) = o;
        o.x = acc[1][i][0] + bb1.x; o.y = acc[1][i][1] + bb1.y;
        o.z = acc[1][i][2] + bb1.z; o.w = acc[1][i][3] + bb1.w;
        *(float4*)(Y1 + rowoff) = o;
        o.x = sigmoidf_(acc[2][i][0] + bb2.x); o.y = sigmoidf_(acc[2][i][1] + bb2.y);
        o.z = sigmoidf_(acc[2][i][2] + bb2.z); o.w = sigmoidf_(acc[2][i][3] + bb2.w);
        *(float4*)(Y2 + rowoff) = o;
        o.x = __expf(acc[3][i][0] + bb3.x); o.y = __expf(acc[3][i][1] + bb3.y);
        o.z = __expf(acc[3][i][2] + bb3.z); o.w = __expf(acc[3][i][3] + bb3.w);
        *(float4*)(Y3 + rowoff) = o;
    }
}

// ---------------------------------------------------------------------------
// Output GEMM: out = (num * invden) @ Wo^T + bo  (invden folded into A-load)
// ---------------------------------------------------------------------------
__global__ __launch_bounds__(256) void out_gemm(
    const float* __restrict__ X, const float* __restrict__ W,
    const float* __restrict__ bias, float* __restrict__ Y)
{
    __shared__ float As[16][68];
    __shared__ float Bs[16][68];

    const int tid = threadIdx.x;
    const int tx = tid & 15;
    const int ty = tid >> 4;
    const int mb = blockIdx.x * 64;
    const int nb = blockIdx.y * 64;
    const int lr = tid >> 2;
    const int lk = (tid & 3) * 4;

    const float dn   = g_den[mb + lr];
    const float invd = 1.0f / fmaxf(fabsf(dn), 1.0f);

    float acc[4][4];
    #pragma unroll
    for (int i = 0; i < 4; ++i)
        #pragma unroll
        for (int j = 0; j < 4; ++j) acc[i][j] = 0.0f;

    for (int k0 = 0; k0 < Dn; k0 += 16) {
        float4 a = *(const float4*)(X + (size_t)(mb + lr) * Dn + k0 + lk);
        const float4 w = *(const float4*)(W + (size_t)(nb + lr) * Dn + k0 + lk);
        a.x *= invd; a.y *= invd; a.z *= invd; a.w *= invd;
        __syncthreads();
        As[lk+0][lr] = a.x; As[lk+1][lr] = a.y; As[lk+2][lr] = a.z; As[lk+3][lr] = a.w;
        Bs[lk+0][lr] = w.x; Bs[lk+1][lr] = w.y; Bs[lk+2][lr] = w.z; Bs[lk+3][lr] = w.w;
        __syncthreads();

        #pragma unroll
        for (int kk = 0; kk < 16; ++kk) {
            const float4 av = *(const float4*)&As[kk][ty * 4];
            const float4 bv = *(const float4*)&Bs[kk][tx * 4];
            const float aa[4] = {av.x, av.y, av.z, av.w};
            const float bb[4] = {bv.x, bv.y, bv.z, bv.w};
            #pragma unroll
            for (int i = 0; i < 4; ++i)
                #pragma unroll
                for (int j = 0; j < 4; ++j)
                    acc[i][j] = fmaf(aa[i], bb[j], acc[i][j]);
        }
    }

    const float4 bbv = *(const float4*)(bias + nb + tx * 4);
    #pragma unroll
    for (int i = 0; i < 4; ++i) {
        const size_t rowoff = (size_t)(mb + ty * 4 + i) * Dn + nb + tx * 4;
        float4 o;
        o.x = acc[i][0] + bbv.x; o.y = acc[i][1] + bbv.y;
        o.z = acc[i][2] + bbv.z; o.w = acc[i][3] + bbv.w;
        *(float4*)(Y + rowoff) = o;
    }
}

// ---------------------------------------------------------------------------
// Pass 1: per-segment summaries. Grid (NS, 9, B). 32 rows/block (8/wave).
//  gy<8 : U_seg (32 rows x 256) + A_end[r] = Π f.
//  gy==8: u_n = f⊙u + i⊙k from zero; a_n = Πf (elementwise, 256 dims).
// ---------------------------------------------------------------------------
__global__ __launch_bounds__(256) void seg_summary(
    const float* __restrict__ Pf, const float* __restrict__ Pi,
    const float* __restrict__ Pk, const float* __restrict__ Pq,
    float* __restrict__ U, float* __restrict__ Aend,
    float* __restrict__ un, float* __restrict__ an)
{
    const int m  = blockIdx.x;
    const int gy = blockIdx.y;
    const int b  = blockIdx.z;
    const size_t base = (size_t)b * Sn * Dn + (size_t)m * LS * Dn;
    const int tid = threadIdx.x;

    if (gy == 8) {
        const int c = tid;
        float u = 0.0f, a = 1.0f;
        #pragma unroll 4
        for (int t = 0; t < LS; ++t) {
            const size_t off = base + (size_t)t * Dn + c;
            const float f  = Pf[off];
            const float iv = Pi[off];
            const float kv = Pk[off];
            u = fmaf(f, u, iv * kv);
            a *= f;
        }
        const size_t s = ((size_t)b * NS + m) * Dn + c;
        un[s] = u;
        an[s] = a;
        return;
    }

    const int lane = tid & 63;
    const int wv   = tid >> 6;
    const int r0   = gy * 32 + wv * 8;   // 8 rows per wave
    const int c0   = lane * 4;

    float C[8][4];
    float a[8];
    #pragma unroll
    for (int r = 0; r < 8; ++r) {
        a[r] = 1.0f;
        #pragma unroll
        for (int j = 0; j < 4; ++j) C[r][j] = 0.0f;
    }

    #pragma unroll 2
    for (int t = 0; t < LS; ++t) {
        const size_t off = base + (size_t)t * Dn;
        const float4 k4  = *(const float4*)(Pk + off + c0);
        const float4 fr0 = *(const float4*)(Pf + off + r0);
        const float4 fr1 = *(const float4*)(Pf + off + r0 + 4);
        const float4 ir0 = *(const float4*)(Pi + off + r0);
        const float4 ir1 = *(const float4*)(Pi + off + r0 + 4);
        const float4 vr0 = *(const float4*)(Pq + off + r0);      // v = q proj
        const float4 vr1 = *(const float4*)(Pq + off + r0 + 4);
        const float fv[8] = {fr0.x, fr0.y, fr0.z, fr0.w, fr1.x, fr1.y, fr1.z, fr1.w};
        const float iv[8] = {ir0.x, ir0.y, ir0.z, ir0.w, ir1.x, ir1.y, ir1.z, ir1.w};
        const float vv[8] = {vr0.x, vr0.y, vr0.z, vr0.w, vr1.x, vr1.y, vr1.z, vr1.w};
        #pragma unroll
        for (int r = 0; r < 8; ++r) {
            const float wr = iv[r] * vv[r];
            C[r][0] = fmaf(fv[r], C[r][0], wr * k4.x);
            C[r][1] = fmaf(fv[r], C[r][1], wr * k4.y);
            C[r][2] = fmaf(fv[r], C[r][2], wr * k4.z);
            C[r][3] = fmaf(fv[r], C[r][3], wr * k4.w);
            a[r] *= fv[r];
        }
    }

    float* Ub = U + (((size_t)b * NS + m) * Dn + r0) * Dn + c0;
    #pragma unroll
    for (int r = 0; r < 8; ++r)
        *(float4*)(Ub + r * Dn) = make_float4(C[r][0], C[r][1], C[r][2], C[r][3]);
    if (lane < 8) {
        const float av = (lane == 0) ? a[0] : (lane == 1) ? a[1] : (lane == 2) ? a[2]
                       : (lane == 3) ? a[3] : (lane == 4) ? a[4] : (lane == 5) ? a[5]
                       : (lane == 6) ? a[6] : a[7];
        Aend[((size_t)b * NS + m) * Dn + r0 + lane] = av;
    }
}

// ---------------------------------------------------------------------------
// Pass 2: per-segment scan with composed carry-in. Grid (NS, 17, B).
// 16 rows/block (4/wave). gx==16: denominator duty.
// Reductions use the multi-value split butterfly (32 shfl per 8-step chunk).
// ---------------------------------------------------------------------------
__global__ __launch_bounds__(256) void seg_scan(
    const float* __restrict__ Pf, const float* __restrict__ Pi,
    const float* __restrict__ Pk, const float* __restrict__ Pq,
    const float* __restrict__ U, const float* __restrict__ Aend,
    const float* __restrict__ un, const float* __restrict__ an,
    float* __restrict__ Pnum)
{
    __shared__ float dpart[4][16];

    const int m  = blockIdx.x;
    const int gx = blockIdx.y;
    const int b  = blockIdx.z;
    const size_t base = (size_t)b * Sn * Dn + (size_t)m * LS * Dn;
    const int tid  = threadIdx.x;
    const int lane = tid & 63;
    const int wv   = tid >> 6;

    if (gx == 16) {
        const int c = tid;
        float n = 0.0f, d = 1.0f;
        for (int j = m - 1; j >= 0; --j) {
            const size_t sj = ((size_t)b * NS + j) * Dn + c;
            n = fmaf(d, un[sj], n);
            d *= an[sj];
        }
        for (int t0 = 0; t0 < LS; t0 += 16) {
            float p[16];
            #pragma unroll
            for (int j = 0; j < 16; ++j) {
                const size_t off = base + (size_t)(t0 + j) * Dn + c;
                n = fmaf(Pf[off], n, Pi[off] * Pk[off]);
                p[j] = n * Pq[off];
            }
            multi_reduce16(p, lane);
            if ((lane & 3) == 0) dpart[wv][(lane >> 2) & 15] = p[0];
            __syncthreads();
            if (tid < 16)
                g_den[b * Sn + m * LS + t0 + tid] =
                    dpart[0][tid] + dpart[1][tid] + dpart[2][tid] + dpart[3][tid];
            __syncthreads();
        }
        return;
    }

    const int r0 = gx * 16 + wv * 4;   // 4 rows per wave
    const int c0 = lane * 4;

    // ---- compose carry-in state ----
    float C0[4] = {0,0,0,0}, C1[4] = {0,0,0,0}, C2[4] = {0,0,0,0}, C3[4] = {0,0,0,0};
    float d0 = 1.f, d1 = 1.f, d2 = 1.f, d3 = 1.f;
    for (int j = m - 1; j >= 0; --j) {
        const float* Ub = U + (((size_t)b * NS + j) * Dn + r0) * Dn + c0;
        const float4 u0 = *(const float4*)(Ub + 0 * Dn);
        const float4 u1 = *(const float4*)(Ub + 1 * Dn);
        const float4 u2 = *(const float4*)(Ub + 2 * Dn);
        const float4 u3 = *(const float4*)(Ub + 3 * Dn);
        C0[0] = fmaf(d0, u0.x, C0[0]); C0[1] = fmaf(d0, u0.y, C0[1]);
        C0[2] = fmaf(d0, u0.z, C0[2]); C0[3] = fmaf(d0, u0.w, C0[3]);
        C1[0] = fmaf(d1, u1.x, C1[0]); C1[1] = fmaf(d1, u1.y, C1[1]);
        C1[2] = fmaf(d1, u1.z, C1[2]); C1[3] = fmaf(d1, u1.w, C1[3]);
        C2[0] = fmaf(d2, u2.x, C2[0]); C2[1] = fmaf(d2, u2.y, C2[1]);
        C2[2] = fmaf(d2, u2.z, C2[2]); C2[3] = fmaf(d2, u2.w, C2[3]);
        C3[0] = fmaf(d3, u3.x, C3[0]); C3[1] = fmaf(d3, u3.y, C3[1]);
        C3[2] = fmaf(d3, u3.z, C3[2]); C3[3] = fmaf(d3, u3.w, C3[3]);
        const size_t sj = ((size_t)b * NS + j) * Dn + r0;
        d0 *= Aend[sj]; d1 *= Aend[sj + 1]; d2 *= Aend[sj + 2]; d3 *= Aend[sj + 3];
    }

    // ---- 64-step scan, 32-value reductions per 8-step chunk ----
    float* pnum = Pnum + base;
    for (int t0 = 0; t0 < LS; t0 += 8) {
        float v[32];   // v[r*8 + j]
        #pragma unroll
        for (int j = 0; j < 8; ++j) {
            const size_t off = base + (size_t)(t0 + j) * Dn;
            const float4 k4 = *(const float4*)(Pk + off + c0);
            const float4 q4 = *(const float4*)(Pq + off + c0);
            const float4 fr = *(const float4*)(Pf + off + r0);
            const float4 ir = *(const float4*)(Pi + off + r0);
            const float4 vr = *(const float4*)(Pq + off + r0);   // v = q proj

            const float w0 = ir.x * vr.x;
            const float w1 = ir.y * vr.y;
            const float w2 = ir.z * vr.z;
            const float w3 = ir.w * vr.w;
            C0[0] = fmaf(fr.x, C0[0], w0 * k4.x); C0[1] = fmaf(fr.x, C0[1], w0 * k4.y);
            C0[2] = fmaf(fr.x, C0[2], w0 * k4.z); C0[3] = fmaf(fr.x, C0[3], w0 * k4.w);
            C1[0] = fmaf(fr.y, C1[0], w1 * k4.x); C1[1] = fmaf(fr.y, C1[1], w1 * k4.y);
            C1[2] = fmaf(fr.y, C1[2], w1 * k4.z); C1[3] = fmaf(fr.y, C1[3], w1 * k4.w);
            C2[0] = fmaf(fr.z, C2[0], w2 * k4.x); C2[1] = fmaf(fr.z, C2[1], w2 * k4.y);
            C2[2] = fmaf(fr.z, C2[2], w2 * k4.z); C2[3] = fmaf(fr.z, C2[3], w2 * k4.w);
            C3[0] = fmaf(fr.w, C3[0], w3 * k4.x); C3[1] = fmaf(fr.w, C3[1], w3 * k4.y);
            C3[2] = fmaf(fr.w, C3[2], w3 * k4.z); C3[3] = fmaf(fr.w, C3[3], w3 * k4.w);

            float a0 = C0[0] * q4.x; a0 = fmaf(C0[1], q4.y, a0);
            a0 = fmaf(C0[2], q4.z, a0); a0 = fmaf(C0[3], q4.w, a0);
            float a1 = C1[0] * q4.x; a1 = fmaf(C1[1], q4.y, a1);
            a1 = fmaf(C1[2], q4.z, a1); a1 = fmaf(C1[3], q4.w, a1);
            float a2 = C2[0] * q4.x; a2 = fmaf(C2[1], q4.y, a2);
            a2 = fmaf(C2[2], q4.z, a2); a2 = fmaf(C2[3], q4.w, a2);
            float a3 = C3[0] * q4.x; a3 = fmaf(C3[1], q4.y, a3);
            a3 = fmaf(C3[2], q4.z, a3); a3 = fmaf(C3[3], q4.w, a3);
            v[0 * 8 + j] = a0; v[1 * 8 + j] = a1; v[2 * 8 + j] = a2; v[3 * 8 + j] = a3;
        }

        multi_reduce32(v, lane);

        // lane L (even) holds sum for id=(L>>1)&31; id = r*8 + j
        if ((lane & 1) == 0) {
            const int id = (lane >> 1) & 31;
            const int r  = id >> 3;
            const int j  = id & 7;
            pnum[(size_t)(t0 + j) * Dn + r0 + r] = v[0];
        }
    }
}

} // anonymous namespace

extern "C" void kernel_launch(void* const* d_in, const int* in_sizes, int n_in,
                              void* d_out, int out_size, void* d_ws, size_t ws_size,
                              hipStream_t stream)
{
    const float* x  = (const float*)d_in[0];
    const float* Wq = (const float*)d_in[1];  const float* bq = (const float*)d_in[2];
    const float* Wk = (const float*)d_in[3];  const float* bk = (const float*)d_in[4];
    // d_in[5]=Wv, d_in[6]=bv unused (reference uses W_q for v)
    const float* Wf = (const float*)d_in[7];  const float* bf = (const float*)d_in[8];
    const float* Wi = (const float*)d_in[9];  const float* bi = (const float*)d_in[10];
    const float* Wo = (const float*)d_in[11]; const float* bo = (const float*)d_in[12];
    float* out = (float*)d_out;

    float* ws = (float*)d_ws;
    const size_t sz = (size_t)Mn * Dn;           // 2,097,152 floats (8 MB)
    float* Pq = ws;
    float* Pk = ws + sz;
    float* Pf = ws + 2 * sz;
    float* Pi = ws + 3 * sz;
    float* Pn = ws + 4 * sz;                     // raw numerators
    float* U    = ws + 5 * sz;                   // [B][NS][D][D] = 32 MB
    float* Aend = U + (size_t)Bn * NS * Dn * Dn; // [B][NS][D]
    float* un   = Aend + (size_t)Bn * NS * Dn;   // [B][NS][D]
    float* an   = un   + (size_t)Bn * NS * Dn;   // [B][NS][D]

    proj_gemm<<<dim3(Mn / 64, Dn / 64), 256, 0, stream>>>(
        x, Wq, bq, Wk, bk, Wf, bf, Wi, bi, Pq, Pk, Pf, Pi);

    seg_summary<<<dim3(NS, 9, Bn), 256, 0, stream>>>(
        Pf, Pi, Pk, Pq, U, Aend, un, an);

    seg_scan<<<dim3(NS, 17, Bn), 256, 0, stream>>>(
        Pf, Pi, Pk, Pq, U, Aend, un, an, Pn);

    out_gemm<<<dim3(Mn / 64, Dn / 64), 256, 0, stream>>>(Pn, Wo, bo, out);
}

// Round 8
// 276.698 us; speedup vs baseline: 2.0760x; 1.1880x over previous
//
#include <hip/hip_runtime.h>
#include <math.h>

namespace {

constexpr int Bn = 8;
constexpr int Sn = 1024;
constexpr int Dn = 256;
constexpr int Mn = Bn * Sn;    // 8192 rows
constexpr int L  = 32;         // chunk length
constexpr int NSEG = Sn / L;   // 32 chunks

__device__ float g_den[Bn * Sn];   // raw n·q per (b,t); clamp applied in out_gemm

__device__ __forceinline__ float sigmoidf_(float x) {
    return 1.0f / (1.0f + __expf(-x));
}

// 16-value split butterfly over 64 lanes (HW-validated in r7).
// Result: lane L holds sum of value id=(L>>2)&15.
__device__ __forceinline__ void multi_reduce16(float v[16], int lane) {
    {   const bool hi = (lane & 32) != 0;
        #pragma unroll
        for (int i = 0; i < 8; ++i) {
            const float send = hi ? v[i] : v[i + 8];
            const float recv = __shfl_xor(send, 32, 64);
            v[i] = (hi ? v[i + 8] : v[i]) + recv;
        } }
    {   const bool hi = (lane & 16) != 0;
        #pragma unroll
        for (int i = 0; i < 4; ++i) {
            const float send = hi ? v[i] : v[i + 4];
            const float recv = __shfl_xor(send, 16, 64);
            v[i] = (hi ? v[i + 4] : v[i]) + recv;
        } }
    {   const bool hi = (lane & 8) != 0;
        #pragma unroll
        for (int i = 0; i < 2; ++i) {
            const float send = hi ? v[i] : v[i + 2];
            const float recv = __shfl_xor(send, 8, 64);
            v[i] = (hi ? v[i + 2] : v[i]) + recv;
        } }
    {   const bool hi = (lane & 4) != 0;
        const float send = hi ? v[0] : v[1];
        const float recv = __shfl_xor(send, 4, 64);
        v[0] = (hi ? v[1] : v[0]) + recv;
    }
    v[0] += __shfl_xor(v[0], 2, 64);
    v[0] += __shfl_xor(v[0], 1, 64);
}

// ---------------------------------------------------------------------------
// Fused projection GEMM: Y_m = act_m(X @ W_m^T + b_m) for m in {q,k,f,i}
// ---------------------------------------------------------------------------
__global__ __launch_bounds__(256) void proj_gemm(
    const float* __restrict__ X,
    const float* __restrict__ W0, const float* __restrict__ b0,
    const float* __restrict__ W1, const float* __restrict__ b1,
    const float* __restrict__ W2, const float* __restrict__ b2,
    const float* __restrict__ W3, const float* __restrict__ b3,
    float* __restrict__ Y0, float* __restrict__ Y1,
    float* __restrict__ Y2, float* __restrict__ Y3)
{
    __shared__ float As[16][68];
    __shared__ float Bs[4][16][68];

    const int tid = threadIdx.x;
    const int tx = tid & 15;
    const int ty = tid >> 4;
    const int mb = blockIdx.x * 64;
    const int nb = blockIdx.y * 64;
    const int lr = tid >> 2;
    const int lk = (tid & 3) * 4;

    float acc[4][4][4];
    #pragma unroll
    for (int m = 0; m < 4; ++m)
        #pragma unroll
        for (int i = 0; i < 4; ++i)
            #pragma unroll
            for (int j = 0; j < 4; ++j) acc[m][i][j] = 0.0f;

    for (int k0 = 0; k0 < Dn; k0 += 16) {
        const float4 a  = *(const float4*)(X  + (size_t)(mb + lr) * Dn + k0 + lk);
        const float4 w0 = *(const float4*)(W0 + (size_t)(nb + lr) * Dn + k0 + lk);
        const float4 w1 = *(const float4*)(W1 + (size_t)(nb + lr) * Dn + k0 + lk);
        const float4 w2 = *(const float4*)(W2 + (size_t)(nb + lr) * Dn + k0 + lk);
        const float4 w3 = *(const float4*)(W3 + (size_t)(nb + lr) * Dn + k0 + lk);
        __syncthreads();
        As[lk+0][lr] = a.x;  As[lk+1][lr] = a.y;  As[lk+2][lr] = a.z;  As[lk+3][lr] = a.w;
        Bs[0][lk+0][lr] = w0.x; Bs[0][lk+1][lr] = w0.y; Bs[0][lk+2][lr] = w0.z; Bs[0][lk+3][lr] = w0.w;
        Bs[1][lk+0][lr] = w1.x; Bs[1][lk+1][lr] = w1.y; Bs[1][lk+2][lr] = w1.z; Bs[1][lk+3][lr] = w1.w;
        Bs[2][lk+0][lr] = w2.x; Bs[2][lk+1][lr] = w2.y; Bs[2][lk+2][lr] = w2.z; Bs[2][lk+3][lr] = w2.w;
        Bs[3][lk+0][lr] = w3.x; Bs[3][lk+1][lr] = w3.y; Bs[3][lk+2][lr] = w3.z; Bs[3][lk+3][lr] = w3.w;
        __syncthreads();

        #pragma unroll
        for (int kk = 0; kk < 16; ++kk) {
            const float4 av = *(const float4*)&As[kk][ty * 4];
            const float aa[4] = {av.x, av.y, av.z, av.w};
            #pragma unroll
            for (int m = 0; m < 4; ++m) {
                const float4 bv = *(const float4*)&Bs[m][kk][tx * 4];
                const float bb[4] = {bv.x, bv.y, bv.z, bv.w};
                #pragma unroll
                for (int i = 0; i < 4; ++i)
                    #pragma unroll
                    for (int j = 0; j < 4; ++j)
                        acc[m][i][j] = fmaf(aa[i], bb[j], acc[m][i][j]);
            }
        }
    }

    const float4 bb0 = *(const float4*)(b0 + nb + tx * 4);
    const float4 bb1 = *(const float4*)(b1 + nb + tx * 4);
    const float4 bb2 = *(const float4*)(b2 + nb + tx * 4);
    const float4 bb3 = *(const float4*)(b3 + nb + tx * 4);

    #pragma unroll
    for (int i = 0; i < 4; ++i) {
        const size_t rowoff = (size_t)(mb + ty * 4 + i) * Dn + nb + tx * 4;
        float4 o;
        o.x = acc[0][i][0] + bb0.x; o.y = acc[0][i][1] + bb0.y;
        o.z = acc[0][i][2] + bb0.z; o.w = acc[0][i][3] + bb0.w;
        *(float4*)(Y0 + rowoff) = o;
        o.x = acc[1][i][0] + bb1.x; o.y = acc[1][i][1] + bb1.y;
        o.z = acc[1][i][2] + bb1.z; o.w = acc[1][i][3] + bb1.w;
        *(float4*)(Y1 + rowoff) = o;
        o.x = sigmoidf_(acc[2][i][0] + bb2.x); o.y = sigmoidf_(acc[2][i][1] + bb2.y);
        o.z = sigmoidf_(acc[2][i][2] + bb2.z); o.w = sigmoidf_(acc[2][i][3] + bb2.w);
        *(float4*)(Y2 + rowoff) = o;
        o.x = __expf(acc[3][i][0] + bb3.x); o.y = __expf(acc[3][i][1] + bb3.y);
        o.z = __expf(acc[3][i][2] + bb3.z); o.w = __expf(acc[3][i][3] + bb3.w);
        *(float4*)(Y3 + rowoff) = o;
    }
}

// ---------------------------------------------------------------------------
// Output GEMM: out = (num * invden) @ Wo^T + bo  (invden folded into A-load)
// ---------------------------------------------------------------------------
__global__ __launch_bounds__(256) void out_gemm(
    const float* __restrict__ X, const float* __restrict__ W,
    const float* __restrict__ bias, float* __restrict__ Y)
{
    __shared__ float As[16][68];
    __shared__ float Bs[16][68];

    const int tid = threadIdx.x;
    const int tx = tid & 15;
    const int ty = tid >> 4;
    const int mb = blockIdx.x * 64;
    const int nb = blockIdx.y * 64;
    const int lr = tid >> 2;
    const int lk = (tid & 3) * 4;

    const float dn   = g_den[mb + lr];
    const float invd = 1.0f / fmaxf(fabsf(dn), 1.0f);

    float acc[4][4];
    #pragma unroll
    for (int i = 0; i < 4; ++i)
        #pragma unroll
        for (int j = 0; j < 4; ++j) acc[i][j] = 0.0f;

    for (int k0 = 0; k0 < Dn; k0 += 16) {
        float4 a = *(const float4*)(X + (size_t)(mb + lr) * Dn + k0 + lk);
        const float4 w = *(const float4*)(W + (size_t)(nb + lr) * Dn + k0 + lk);
        a.x *= invd; a.y *= invd; a.z *= invd; a.w *= invd;
        __syncthreads();
        As[lk+0][lr] = a.x; As[lk+1][lr] = a.y; As[lk+2][lr] = a.z; As[lk+3][lr] = a.w;
        Bs[lk+0][lr] = w.x; Bs[lk+1][lr] = w.y; Bs[lk+2][lr] = w.z; Bs[lk+3][lr] = w.w;
        __syncthreads();

        #pragma unroll
        for (int kk = 0; kk < 16; ++kk) {
            const float4 av = *(const float4*)&As[kk][ty * 4];
            const float4 bv = *(const float4*)&Bs[kk][tx * 4];
            const float aa[4] = {av.x, av.y, av.z, av.w};
            const float bb[4] = {bv.x, bv.y, bv.z, bv.w};
            #pragma unroll
            for (int i = 0; i < 4; ++i)
                #pragma unroll
                for (int j = 0; j < 4; ++j)
                    acc[i][j] = fmaf(aa[i], bb[j], acc[i][j]);
        }
    }

    const float4 bbv = *(const float4*)(bias + nb + tx * 4);
    #pragma unroll
    for (int i = 0; i < 4; ++i) {
        const size_t rowoff = (size_t)(mb + ty * 4 + i) * Dn + nb + tx * 4;
        float4 o;
        o.x = acc[i][0] + bbv.x; o.y = acc[i][1] + bbv.y;
        o.z = acc[i][2] + bbv.z; o.w = acc[i][3] + bbv.w;
        *(float4*)(Y + rowoff) = o;
    }
}

// ---------------------------------------------------------------------------
// gate_prep: per (chunk m, batch b), thread = r. Elementwise chunk scans:
//   G[τ,r] = Π_{u<=τ} f ;  Ṽ[τ,r] = i·v/G ;  Ñ[τ,r] = Σ i·k/G
//   Aend = G[L-1], un = Aend·Ñ[L-1]
// ---------------------------------------------------------------------------
__global__ __launch_bounds__(256) void gate_prep(
    const float* __restrict__ Pf, const float* __restrict__ Pi,
    const float* __restrict__ Pk, const float* __restrict__ Pq,
    float* __restrict__ Gc, float* __restrict__ Vt, float* __restrict__ Nt,
    float* __restrict__ Aend, float* __restrict__ un)
{
    const int m = blockIdx.x;
    const int b = blockIdx.y;
    const int r = threadIdx.x;
    const size_t base = (size_t)b * Sn * Dn + (size_t)m * L * Dn + r;

    float G = 1.0f, Nacc = 0.0f;
    #pragma unroll 4
    for (int t = 0; t < L; ++t) {
        const size_t off = base + (size_t)t * Dn;
        const float f  = Pf[off];
        const float iv = Pi[off];
        const float kv = Pk[off];
        const float vv = Pq[off];     // v = q projection (Wv unused)
        G *= f;
        const float rG = 1.0f / G;
        Gc[off] = G;
        Vt[off] = iv * vv * rG;
        Nacc = fmaf(iv * kv, rG, Nacc);
        Nt[off] = Nacc;
    }
    const size_t s = ((size_t)b * NSEG + m) * Dn + r;
    Aend[s] = G;
    un[s]   = G * Nacc;
}

// ---------------------------------------------------------------------------
// ut_gemm: UT[b,m][c,r] = Aend[r] * Σ_σ K[σ,c]·Ṽ[σ,r]   (chunk from-zero state,
// stored transposed). Grid (Bn*NSEG, 16 tiles of 64x64). K-dim = L = 32.
// ---------------------------------------------------------------------------
__global__ __launch_bounds__(256) void ut_gemm(
    const float* __restrict__ Pk, const float* __restrict__ Vt,
    const float* __restrict__ Aend, float* __restrict__ UT)
{
    __shared__ float As[L][68];   // K^T tile: As[σ][c]
    __shared__ float Bs[L][68];   // Ṽ tile:  Bs[σ][r]

    const int bm   = blockIdx.x;           // b*NSEG + m
    const int tile = blockIdx.y;
    const int cb   = (tile >> 2) * 64;
    const int rb   = (tile & 3) * 64;
    const int b    = bm >> 5;
    const int m    = bm & 31;
    const size_t kb = (size_t)b * Sn * Dn + (size_t)m * L * Dn;
    const int tid = threadIdx.x;

    #pragma unroll
    for (int n = 0; n < 8; ++n) {
        const int e  = n * 256 + tid;
        const int sg = e >> 6;
        const int cc = e & 63;
        As[sg][cc] = Pk[kb + (size_t)sg * Dn + cb + cc];
        Bs[sg][cc] = Vt[kb + (size_t)sg * Dn + rb + cc];
    }
    __syncthreads();

    const int tx = tid & 15;
    const int ty = tid >> 4;
    float acc[4][4];
    #pragma unroll
    for (int i = 0; i < 4; ++i)
        #pragma unroll
        for (int j = 0; j < 4; ++j) acc[i][j] = 0.0f;

    #pragma unroll
    for (int sg = 0; sg < L; ++sg) {
        const float4 a4 = *(const float4*)&As[sg][ty * 4];
        const float4 b4 = *(const float4*)&Bs[sg][tx * 4];
        const float aa[4] = {a4.x, a4.y, a4.z, a4.w};
        const float bb[4] = {b4.x, b4.y, b4.z, b4.w};
        #pragma unroll
        for (int i = 0; i < 4; ++i)
            #pragma unroll
            for (int j = 0; j < 4; ++j)
                acc[i][j] = fmaf(aa[i], bb[j], acc[i][j]);
    }

    const float4 g4 = *(const float4*)(Aend + (size_t)bm * Dn + rb + tx * 4);
    float* ub = UT + (size_t)bm * Dn * Dn;
    #pragma unroll
    for (int i = 0; i < 4; ++i) {
        float4 o;
        o.x = acc[i][0] * g4.x; o.y = acc[i][1] * g4.y;
        o.z = acc[i][2] * g4.z; o.w = acc[i][3] * g4.w;
        *(float4*)(ub + (size_t)(cb + ty * 4 + i) * Dn + rb + tx * 4) = o;
    }
}

// ---------------------------------------------------------------------------
// compose: sequential over chunks (32 steps, elementwise).
//  gx<64 : CinT[b,m][c,r] = carry state before chunk m (transposed layout).
//  gx==64: nin[b,m][r] likewise from (Aend, un).
// ---------------------------------------------------------------------------
__global__ __launch_bounds__(256) void compose(
    const float* __restrict__ UT, const float* __restrict__ Aend,
    const float* __restrict__ un,
    float* __restrict__ CinT, float* __restrict__ nin)
{
    const int gx = blockIdx.x;
    const int b  = blockIdx.y;
    const int tid = threadIdx.x;

    if (gx == 64) {
        const int r = tid;
        float acc = 0.0f;
        for (int m = 0; m < NSEG; ++m) {
            const size_t s = ((size_t)b * NSEG + m) * Dn + r;
            nin[s] = acc;
            acc = fmaf(Aend[s], acc, un[s]);
        }
        return;
    }

    const int id = gx * 256 + tid;       // 0..16383
    const int c  = id >> 6;
    const int r4 = (id & 63) * 4;

    float4 acc = make_float4(0.f, 0.f, 0.f, 0.f);
    for (int m = 0; m < NSEG; ++m) {
        const size_t bm  = (size_t)b * NSEG + m;
        const size_t idx = bm * Dn * Dn + (size_t)c * Dn + r4;
        *(float4*)(CinT + idx) = acc;
        const float4 a4 = *(const float4*)(Aend + bm * Dn + r4);
        const float4 u4 = *(const float4*)(UT + idx);
        acc.x = fmaf(a4.x, acc.x, u4.x);
        acc.y = fmaf(a4.y, acc.y, u4.y);
        acc.z = fmaf(a4.z, acc.z, u4.z);
        acc.w = fmaf(a4.w, acc.w, u4.w);
    }
}

// ---------------------------------------------------------------------------
// s_gemm: S[b,m][τ,σ] = k_σ·q_τ for σ<=τ else 0.  Grid (NSEG, Bn), 256 thr,
// 4 outputs/thread (τ = tid/8, σ4 = (tid%8)*4).
// ---------------------------------------------------------------------------
__global__ __launch_bounds__(256) void s_gemm(
    const float* __restrict__ Pk, const float* __restrict__ Pq,
    float* __restrict__ Ssm)
{
    const int m = blockIdx.x;
    const int b = blockIdx.y;
    const size_t qb = (size_t)b * Sn * Dn + (size_t)m * L * Dn;
    const int tid = threadIdx.x;
    const int tau = tid >> 3;
    const int s4  = (tid & 7) * 4;

    float a0 = 0.f, a1 = 0.f, a2 = 0.f, a3 = 0.f;
    #pragma unroll 4
    for (int c = 0; c < Dn; c += 4) {
        const float4 q4 = *(const float4*)(Pq + qb + (size_t)tau * Dn + c);
        const float4 k0 = *(const float4*)(Pk + qb + (size_t)(s4 + 0) * Dn + c);
        const float4 k1 = *(const float4*)(Pk + qb + (size_t)(s4 + 1) * Dn + c);
        const float4 k2 = *(const float4*)(Pk + qb + (size_t)(s4 + 2) * Dn + c);
        const float4 k3 = *(const float4*)(Pk + qb + (size_t)(s4 + 3) * Dn + c);
        a0 += q4.x*k0.x + q4.y*k0.y + q4.z*k0.z + q4.w*k0.w;
        a1 += q4.x*k1.x + q4.y*k1.y + q4.z*k1.z + q4.w*k1.w;
        a2 += q4.x*k2.x + q4.y*k2.y + q4.z*k2.z + q4.w*k2.w;
        a3 += q4.x*k3.x + q4.y*k3.y + q4.z*k3.z + q4.w*k3.w;
    }
    float* out = Ssm + ((size_t)b * NSEG + m) * L * L + (size_t)tau * L + s4;
    out[0] = (s4 + 0 <= tau) ? a0 : 0.0f;
    out[1] = (s4 + 1 <= tau) ? a1 : 0.0f;
    out[2] = (s4 + 2 <= tau) ? a2 : 0.0f;
    out[3] = (s4 + 3 <= tau) ? a3 : 0.0f;
}

// ---------------------------------------------------------------------------
// num_gemm: Pnum[τ,r] = G[τ,r]·( Σ_σ S[τ,σ]Ṽ[σ,r] + Σ_c Q[τ,c]CinT[c,r] )
// Grid (2, NSEG, Bn): 32τ x 128r per block. 256 thr: tx=tid&31 -> r4,
// ty=tid>>5 -> 4 τ's.
// ---------------------------------------------------------------------------
__global__ __launch_bounds__(256) void num_gemm(
    const float* __restrict__ Pq, const float* __restrict__ Vt,
    const float* __restrict__ Gc, const float* __restrict__ Ssm,
    const float* __restrict__ CinT, float* __restrict__ Pnum)
{
    __shared__ float Sld[L][33];
    __shared__ float Qld[L][257];

    const int rb = blockIdx.x * 128;
    const int m  = blockIdx.y;
    const int b  = blockIdx.z;
    const size_t qb = (size_t)b * Sn * Dn + (size_t)m * L * Dn;
    const size_t ub = ((size_t)b * NSEG + m) * Dn * Dn;
    const size_t sb = ((size_t)b * NSEG + m) * L * L;
    const int tid = threadIdx.x;

    #pragma unroll
    for (int n = 0; n < 4; ++n) {
        const int e = n * 256 + tid;
        Sld[e >> 5][e & 31] = Ssm[sb + e];
    }
    #pragma unroll
    for (int n = 0; n < L; ++n)
        Qld[n][tid] = Pq[qb + (size_t)n * Dn + tid];
    __syncthreads();

    const int tx = tid & 31;
    const int ty = tid >> 5;
    const int r4 = rb + tx * 4;
    const int t4 = ty * 4;

    float4 acc[4];
    #pragma unroll
    for (int i = 0; i < 4; ++i) acc[i] = make_float4(0.f, 0.f, 0.f, 0.f);

    // phase 1: S @ Ṽ  (K = 32)
    #pragma unroll 4
    for (int sg = 0; sg < L; ++sg) {
        const float4 v4 = *(const float4*)(Vt + qb + (size_t)sg * Dn + r4);
        #pragma unroll
        for (int i = 0; i < 4; ++i) {
            const float s = Sld[t4 + i][sg];
            acc[i].x = fmaf(s, v4.x, acc[i].x);
            acc[i].y = fmaf(s, v4.y, acc[i].y);
            acc[i].z = fmaf(s, v4.z, acc[i].z);
            acc[i].w = fmaf(s, v4.w, acc[i].w);
        }
    }

    // phase 2: Q @ Cin^T  (K = 256)
    #pragma unroll 8
    for (int c = 0; c < Dn; ++c) {
        const float4 ct = *(const float4*)(CinT + ub + (size_t)c * Dn + r4);
        #pragma unroll
        for (int i = 0; i < 4; ++i) {
            const float q = Qld[t4 + i][c];
            acc[i].x = fmaf(q, ct.x, acc[i].x);
            acc[i].y = fmaf(q, ct.y, acc[i].y);
            acc[i].z = fmaf(q, ct.z, acc[i].z);
            acc[i].w = fmaf(q, ct.w, acc[i].w);
        }
    }

    #pragma unroll
    for (int i = 0; i < 4; ++i) {
        const size_t off = qb + (size_t)(t4 + i) * Dn + r4;
        const float4 g4 = *(const float4*)(Gc + off);
        float4 o;
        o.x = acc[i].x * g4.x; o.y = acc[i].y * g4.y;
        o.z = acc[i].z * g4.z; o.w = acc[i].w * g4.w;
        *(float4*)(Pnum + off) = o;
    }
}

// ---------------------------------------------------------------------------
// den_kernel: g_den[b,t] = Σ_r q[t,r]·G[t,r]·(nin[m,r] + Ñ[t,r]),  m = t/L.
// Grid (8, Bn): 128 τ per block, 32 per wave, batched 16 into multi_reduce16.
// ---------------------------------------------------------------------------
__global__ __launch_bounds__(256) void den_kernel(
    const float* __restrict__ Pq, const float* __restrict__ Gc,
    const float* __restrict__ Nt, const float* __restrict__ nin)
{
    const int gx = blockIdx.x;
    const int b  = blockIdx.y;
    const int tid  = threadIdx.x;
    const int lane = tid & 63;
    const int wv   = tid >> 6;
    const int c4   = lane * 4;

    for (int batch = 0; batch < 2; ++batch) {
        const int tbase = gx * 128 + wv * 32 + batch * 16;
        float p[16];
        #pragma unroll
        for (int j = 0; j < 16; ++j) {
            const int t = tbase + j;
            const int m = t >> 5;
            const size_t off = (size_t)b * Sn * Dn + (size_t)t * Dn + c4;
            const float4 q4 = *(const float4*)(Pq + off);
            const float4 g4 = *(const float4*)(Gc + off);
            const float4 n4 = *(const float4*)(Nt + off);
            const float4 i4 = *(const float4*)(nin + ((size_t)b * NSEG + m) * Dn + c4);
            p[j] = q4.x * g4.x * (i4.x + n4.x)
                 + q4.y * g4.y * (i4.y + n4.y)
                 + q4.z * g4.z * (i4.z + n4.z)
                 + q4.w * g4.w * (i4.w + n4.w);
        }
        multi_reduce16(p, lane);
        if ((lane & 3) == 0)
            g_den[b * Sn + tbase + ((lane >> 2) & 15)] = p[0];
    }
}

} // anonymous namespace

extern "C" void kernel_launch(void* const* d_in, const int* in_sizes, int n_in,
                              void* d_out, int out_size, void* d_ws, size_t ws_size,
                              hipStream_t stream)
{
    const float* x  = (const float*)d_in[0];
    const float* Wq = (const float*)d_in[1];  const float* bq = (const float*)d_in[2];
    const float* Wk = (const float*)d_in[3];  const float* bk = (const float*)d_in[4];
    // d_in[5]=Wv, d_in[6]=bv unused (reference uses W_q for v)
    const float* Wf = (const float*)d_in[7];  const float* bf = (const float*)d_in[8];
    const float* Wi = (const float*)d_in[9];  const float* bi = (const float*)d_in[10];
    const float* Wo = (const float*)d_in[11]; const float* bo = (const float*)d_in[12];
    float* out = (float*)d_out;

    float* ws = (float*)d_ws;
    const size_t sz = (size_t)Mn * Dn;            // 2,097,152 floats (8 MB)
    float* Pq = ws;
    float* Pk = ws + sz;
    float* Pf = ws + 2 * sz;
    float* Pi = ws + 3 * sz;
    float* Pn = ws + 4 * sz;                      // numerators
    float* Gc = ws + 5 * sz;                      // G cumprod  [b,t,r]
    float* Vt = ws + 6 * sz;                      // Ṽ          [b,t,r]
    float* Nt = ws + 7 * sz;                      // Ñ cumsum   [b,t,r]
    float* UT   = ws + 8 * sz;                    // [b,m][c][r]  8*sz
    float* CinT = ws + 16 * sz;                   // [b,m][c][r]  8*sz
    float* Ssm  = ws + 24 * sz;                   // [b,m][τ][σ]  262144
    float* Aend = Ssm + (size_t)Bn * NSEG * L * L;
    float* un   = Aend + (size_t)Bn * NSEG * Dn;
    float* nin  = un   + (size_t)Bn * NSEG * Dn;

    proj_gemm<<<dim3(Mn / 64, Dn / 64), 256, 0, stream>>>(
        x, Wq, bq, Wk, bk, Wf, bf, Wi, bi, Pq, Pk, Pf, Pi);

    gate_prep<<<dim3(NSEG, Bn), 256, 0, stream>>>(
        Pf, Pi, Pk, Pq, Gc, Vt, Nt, Aend, un);

    ut_gemm<<<dim3(Bn * NSEG, 16), 256, 0, stream>>>(Pk, Vt, Aend, UT);

    compose<<<dim3(65, Bn), 256, 0, stream>>>(UT, Aend, un, CinT, nin);

    s_gemm<<<dim3(NSEG, Bn), 256, 0, stream>>>(Pk, Pq, Ssm);

    num_gemm<<<dim3(2, NSEG, Bn), 256, 0, stream>>>(
        Pq, Vt, Gc, Ssm, CinT, Pn);

    den_kernel<<<dim3(8, Bn), 256, 0, stream>>>(Pq, Gc, Nt, nin);

    out_gemm<<<dim3(Mn / 64, Dn / 64), 256, 0, stream>>>(Pn, Wo, bo, out);
}